// Round 3
// baseline (1250.915 us; speedup 1.0000x reference)
//
#include <hip/hip_runtime.h>

typedef unsigned short u16;
typedef __bf16 bf16x8 __attribute__((ext_vector_type(8)));
typedef float  f32x4  __attribute__((ext_vector_type(4)));
typedef u16    u16x8  __attribute__((ext_vector_type(8)));

// ---------- problem constants ----------
#define BATCH 256
#define TT    197          // tokens
#define TP    256          // padded tokens
#define DD    192          // model dim
#define DHP   64           // padded head dim (real 48)
#define MTOK  (BATCH*TT)   // 50432 rows = 197*256
#define MPAT  (BATCH*196)  // 50176 rows

constexpr size_t BIG_E  = 1024ull*256*256;   // patches 38.5M / mlp-h 38.7M
constexpr size_t TOK_E  = (size_t)MTOK*DD;
constexpr size_t QKV_E  = 1024ull*TP*DHP;    // per q/k/v tensor (padded)

__device__ __forceinline__ float b2f(u16 h){ union{unsigned u; float f;} x; x.u=(unsigned)h<<16; return x.f; }
__device__ __forceinline__ u16 f2b(float f){ union{float f; unsigned u;} x{f}; unsigned r = x.u + 0x7fffu + ((x.u>>16)&1u); return (u16)(r>>16); }
__device__ __forceinline__ bf16x8 as_bf(u16x8 v){ return __builtin_bit_cast(bf16x8, v); }

__device__ __forceinline__ void gload_lds16(const void* g, void* l) {
  __builtin_amdgcn_global_load_lds((__attribute__((address_space(1))) void*)(size_t)g,
                                   (__attribute__((address_space(3))) void*)l, 16, 0, 0);
}

// ---------- 4-wave 256x64-tile MFMA GEMM:  C = A(MxK) @ W(NxK)^T ----------
// Double-buffered staging with COUNTED vmcnt (T3/T4): tile t+1's
// global_load_lds stay in flight across the barrier while tile t computes.
// 5 loads/wave/tile (wave-uniform) -> steady-state wait is vmcnt(5), never 0.
enum { M_F32=0, M_BF16=1, M_QKV=2, M_PATCH=4 };

template<int MODE, bool RELU, bool RES, bool BIAS>
__global__ __launch_bounds__(256)
void gemm4w(const u16* __restrict__ A, const u16* __restrict__ W,
            const float* __restrict__ bias, const u16* __restrict__ res,
            void* __restrict__ Cout, const float* __restrict__ aux,
            int K, int lda, int ldc, int Nreal,
            long bA, long bW, long bC)
{
  __shared__ __align__(16) u16 As[2][256*32];   // 32 KB (double-buffered)
  __shared__ __align__(16) u16 Ws[2][64*32];    // 8 KB
  const int tid  = threadIdx.x;
  const int wv   = tid >> 6;
  const int lane = tid & 63;
  const int m0 = blockIdx.x * 256;
  const int n0 = blockIdx.y * 64;
  const int bz = blockIdx.z;
  const u16* Ab = A + (size_t)bz * (size_t)bA;
  const u16* Wb = W + (size_t)bz * (size_t)bW;

  const int lrow = lane & 15, quad = lane >> 4;
  const int srow = lane >> 2, sseg = lane & 3;

  f32x4 acc[4][4];
  #pragma unroll
  for (int i=0;i<4;i++)
    #pragma unroll
    for (int j=0;j<4;j++) { f32x4 z = {0.f,0.f,0.f,0.f}; acc[i][j] = z; }

  auto stage = [&](int bufi, int k0) {
    #pragma unroll
    for (int i=0;i<4;i++) {
      const u16* ga = Ab + (size_t)(m0 + i*64 + wv*16 + srow)*lda + (k0 + sseg*8);
      gload_lds16(ga, &As[bufi][(i*64 + wv*16)*32]);
    }
    const u16* gw = Wb + (size_t)(n0 + wv*16 + srow)*K + (k0 + sseg*8);
    gload_lds16(gw, &Ws[bufi][(wv*16)*32]);
  };

  const int nt = K >> 5;
  stage(0, 0);                       // prologue: tile 0 in flight (5 loads)
  int cur = 0;
  for (int t = 0; t < nt; ++t) {
    if (t + 1 < nt) {
      stage(cur ^ 1, (t + 1) << 5);  // issue next tile (now 10 in flight)
      asm volatile("s_waitcnt vmcnt(5)" ::: "memory");   // tile t done; t+1 stays in flight
    } else {
      asm volatile("s_waitcnt vmcnt(0)" ::: "memory");   // last tile: drain
    }
    asm volatile("s_barrier" ::: "memory");              // all waves' tile-t loads visible

    bf16x8 af[4], wf[4];
    #pragma unroll
    for (int i=0;i<4;i++) {
      af[i] = *(const bf16x8*)&As[cur][(wv*64 + i*16 + lrow)*32 + quad*8];
      wf[i] = *(const bf16x8*)&Ws[cur][(i*16 + lrow)*32 + quad*8];
    }
    #pragma unroll
    for (int mi=0;mi<4;mi++)
      #pragma unroll
      for (int ni=0;ni<4;ni++)
        acc[mi][ni] = __builtin_amdgcn_mfma_f32_16x16x32_bf16(af[mi], wf[ni], acc[mi][ni], 0,0,0);

    asm volatile("s_waitcnt lgkmcnt(0)" ::: "memory");   // my ds_reads of buf[cur] done
    asm volatile("s_barrier" ::: "memory");              // everyone done before overwrite
    cur ^= 1;
  }

  #pragma unroll
  for (int mi=0;mi<4;mi++) {
    #pragma unroll
    for (int ni=0;ni<4;ni++) {
      #pragma unroll
      for (int r=0;r<4;r++) {
        int row = m0 + wv*64 + mi*16 + quad*4 + r;
        int col = n0 + ni*16 + lrow;
        float v = acc[mi][ni][r];
        if constexpr (MODE == M_F32) {
          if (col < Nreal) {
            if constexpr (BIAS) v += bias[col];
            ((float*)Cout)[(size_t)row*ldc + col] = v;
          }
        } else if constexpr (MODE == M_BF16) {
          if constexpr (BIAS) v += bias[col];
          if constexpr (RES)  v += b2f(res[(size_t)row*ldc + col]);
          if constexpr (RELU) v = v > 0.f ? v : 0.f;
          ((u16*)Cout)[(size_t)bz*(size_t)bC + (size_t)row*ldc + col] = f2b(v);
        } else if constexpr (MODE == M_QKV) {
          v += bias[col];
          int sel = col / 192, rem = col % 192;
          int h = rem / 48, d = rem % 48;
          int b = row / 197, t = row % 197;
          ((u16*)Cout)[(size_t)sel*QKV_E + ((size_t)(b*4 + h)*TP + t)*DHP + d] = f2b(v);
        } else if constexpr (MODE == M_PATCH) {
          int b = row / 196, p = row % 196;
          v += bias[col] + aux[(size_t)(1 + p)*DD + col];
          ((u16*)Cout)[((size_t)(b*197) + 1 + p)*DD + col] = f2b(v);
        }
      }
    }
  }
}

// ---------- fused flash attention: one workgroup per (b,h) ----------
// LDS: K 208x72 (d-pad zeroed), Vt 49x216, P 4x16x72. 60.3 KB total.
#define KSTR 72
#define VSTR 216
#define PSTR 72
#define TKR  208

__global__ __launch_bounds__(256,1)
void flash_k(const u16* __restrict__ Qg, const u16* __restrict__ Kg,
             const u16* __restrict__ Vg, u16* __restrict__ Og)
{
  __shared__ __align__(16) u16 Ks[TKR*KSTR];
  __shared__ __align__(16) u16 Vs[49*VSTR];
  __shared__ __align__(16) u16 Ps[4*16*PSTR];
  const int bh = blockIdx.x;
  const int b = bh >> 2, h = bh & 3;
  const int tid = threadIdx.x, wv = tid >> 6, lane = tid & 63;
  const int lrow = lane & 15, quad = lane >> 4;
  const size_t base = (size_t)bh * TP * DHP;
  const float scale = 0.14433756729740643f;   // 1/sqrt(48)

  // Q fragments (A-layout): t = wv*64 + rg*16 + lrow, k(d) = ka*32 + quad*8
  bf16x8 qf[4][2];
  #pragma unroll
  for (int rg=0; rg<4; rg++)
    #pragma unroll
    for (int ka=0; ka<2; ka++)
      qf[rg][ka] = as_bf(*(const u16x8*)(Qg + base + (size_t)(wv*64+rg*16+lrow)*DHP + ka*32 + quad*8));

  // stage K rows 0..207: segs 0..5 = data, segs 6..7 = zeros (d pad)
  for (int it=0; it<5; it++) {
    int slot = it*256 + tid;
    if (slot < 1248) {
      int t = slot/6, sg = slot - t*6;
      u16x8 v = *(const u16x8*)(Kg + base + (size_t)t*DHP + sg*8);
      *(u16x8*)&Ks[t*KSTR + sg*8] = v;
    }
  }
  {
    u16x8 z = {0,0,0,0,0,0,0,0};
    for (int it=0; it<2; it++) {
      int slot = it*256 + tid;
      if (slot < 416) { int t = slot>>1, sg = 6 + (slot&1);
        *(u16x8*)&Ks[t*KSTR + sg*8] = z; }
    }
  }
  // stage V transposed: Vs[d][t], d<48, t<208
  for (int it=0; it<5; it++) {
    int slot = it*256 + tid;
    if (slot < 1248) {
      int sg = slot/208, t = slot - sg*208;
      u16x8 v = *(const u16x8*)(Vg + base + (size_t)t*DHP + sg*8);
      #pragma unroll
      for (int j=0;j<8;j++) Vs[(sg*8+j)*VSTR + t] = v[j];
    }
  }
  __syncthreads();

  f32x4 o[4][3];
  float m_i[4][4], l_i[4][4];
  #pragma unroll
  for (int rg=0;rg<4;rg++) {
    #pragma unroll
    for (int dg=0;dg<3;dg++) { f32x4 z = {0.f,0.f,0.f,0.f}; o[rg][dg] = z; }
    #pragma unroll
    for (int r=0;r<4;r++) { m_i[rg][r] = -1e30f; l_i[rg][r] = 0.f; }
  }
  u16* Pw = &Ps[wv*16*PSTR];

  #pragma unroll
  for (int c=0; c<4; c++) {
    const int NC = (c<3) ? 4 : 1;     // chunk 3: only cols 192..207 can be valid
    f32x4 s[4][4];
    #pragma unroll
    for (int rg=0;rg<4;rg++)
      #pragma unroll
      for (int cg=0;cg<4;cg++) if (cg < NC) { f32x4 z = {0.f,0.f,0.f,0.f}; s[rg][cg] = z; }

    // S chunk = Q @ K^T
    #pragma unroll
    for (int cg=0;cg<4;cg++) if (cg < NC) {
      #pragma unroll
      for (int ka=0; ka<2; ka++) {
        bf16x8 kf = as_bf(*(const u16x8*)&Ks[(c*64+cg*16+lrow)*KSTR + ka*32 + quad*8]);
        #pragma unroll
        for (int rg=0;rg<4;rg++)
          s[rg][cg] = __builtin_amdgcn_mfma_f32_16x16x32_bf16(qf[rg][ka], kf, s[rg][cg], 0,0,0);
      }
    }

    // online softmax + PV, per row-group
    #pragma unroll
    for (int rg=0;rg<4;rg++) {
      if (c == 3) {
        #pragma unroll
        for (int r=0;r<4;r++) s[rg][0][r] = (lrow >= 5) ? -1e30f : s[rg][0][r];
      }
      float mnew[4], al[4];
      #pragma unroll
      for (int r=0;r<4;r++) {
        float mc = s[rg][0][r];
        #pragma unroll
        for (int cg=1;cg<4;cg++) if (cg < NC) mc = fmaxf(mc, s[rg][cg][r]);
        #pragma unroll
        for (int sh=1; sh<16; sh<<=1) mc = fmaxf(mc, __shfl_xor(mc, sh, 64));
        float mo = m_i[rg][r];
        float mn = fmaxf(mo, mc);
        mnew[r] = mn;
        al[r] = __expf((mo - mn)*scale);
      }
      #pragma unroll
      for (int r=0;r<4;r++) {
        float acc = 0.f;
        #pragma unroll
        for (int cg=0;cg<4;cg++) if (cg < NC) {
          float p = __expf((s[rg][cg][r] - mnew[r])*scale);
          s[rg][cg][r] = p;
          acc += p;
        }
        #pragma unroll
        for (int sh=1; sh<16; sh<<=1) acc += __shfl_xor(acc, sh, 64);
        l_i[rg][r] = l_i[rg][r]*al[r] + acc;
        m_i[rg][r] = mnew[r];
      }
      #pragma unroll
      for (int dg=0;dg<3;dg++)
        #pragma unroll
        for (int r=0;r<4;r++) o[rg][dg][r] *= al[r];

      // P (C-layout) -> LDS (row-major) for A-layout reads
      #pragma unroll
      for (int cg=0;cg<4;cg++) if (cg < NC) {
        #pragma unroll
        for (int r=0;r<4;r++)
          Pw[(quad*4+r)*PSTR + cg*16 + lrow] = f2b(s[rg][cg][r]);
      }
      if (c == 3) {
        #pragma unroll
        for (int r=0;r<4;r++) Pw[(quad*4+r)*PSTR + 16 + lrow] = 0;
      }
      __builtin_amdgcn_s_waitcnt(0xC07F);   // lgkmcnt(0)

      const int NK = (c<3) ? 2 : 1;
      #pragma unroll
      for (int ka=0; ka<2; ka++) if (ka < NK) {
        bf16x8 pf = as_bf(*(const u16x8*)&Pw[lrow*PSTR + ka*32 + quad*8]);
        #pragma unroll
        for (int dg=0;dg<3;dg++) {
          bf16x8 vf = as_bf(*(const u16x8*)&Vs[(dg*16+lrow)*VSTR + c*64 + ka*32 + quad*8]);
          o[rg][dg] = __builtin_amdgcn_mfma_f32_16x16x32_bf16(pf, vf, o[rg][dg], 0,0,0);
        }
      }
      __builtin_amdgcn_s_waitcnt(0xC07F);   // drain reads before next rg overwrites Pw
    }
  }

  // epilogue: O /= l, store rows t<197, cols d<48
  #pragma unroll
  for (int rg=0;rg<4;rg++) {
    #pragma unroll
    for (int r=0;r<4;r++) {
      int t = wv*64 + rg*16 + quad*4 + r;
      if (t < 197) {
        float inv = 1.0f / l_i[rg][r];
        u16* dst = Og + ((size_t)(b*197) + t)*DD + h*48;
        #pragma unroll
        for (int dg=0;dg<3;dg++) dst[dg*16 + lrow] = f2b(o[rg][dg][r]*inv);
      }
    }
  }
}

// ---------- small kernels ----------
// all weight fp32->bf16 conversions in one launch (incl. head pad-to-zero)
__global__ void cvt5_k(const float* __restrict__ a, const float* __restrict__ b,
                       const float* __restrict__ c, const float* __restrict__ d,
                       const float* __restrict__ e,
                       u16* __restrict__ oa, u16* __restrict__ ob, u16* __restrict__ oc,
                       u16* __restrict__ od, u16* __restrict__ oe) {
  int i = blockIdx.x*256 + threadIdx.x;
  if (i < 147456) { oa[i] = f2b(a[i]); return; } i -= 147456;
  if (i < 110592) { ob[i] = f2b(b[i]); return; } i -= 110592;
  if (i < 442368) { oc[i] = f2b(c[i]); return; } i -= 442368;
  if (i < 442368) { od[i] = f2b(d[i]); return; } i -= 442368;
  if (i < 196608) { oe[i] = (i < 192000) ? f2b(e[i]) : (u16)0; }
}

__global__ void im2col_k(const float* __restrict__ x, u16* __restrict__ P) {
  int id = blockIdx.x*256 + threadIdx.x;
  int w8 = id % 28; int r = id / 28;
  int h  = r % 224; r /= 224;
  int c  = r % 3;   int b = r / 3;
  const float* src = x + (((size_t)(b*3 + c)*224 + h)*224 + w8*8);
  float4 a  = *(const float4*)src;
  float4 bb = *(const float4*)(src + 4);
  int pr = h >> 4, i = h & 15, pc = (w8*8) >> 4, j0 = (w8*8) & 15;
  u16* dst = P + ((size_t)(b*196) + pr*14 + pc)*768 + (c*256 + i*16 + j0);
  u16x8 o;
  o[0]=f2b(a.x); o[1]=f2b(a.y); o[2]=f2b(a.z); o[3]=f2b(a.w);
  o[4]=f2b(bb.x); o[5]=f2b(bb.y); o[6]=f2b(bb.z); o[7]=f2b(bb.w);
  *(u16x8*)dst = o;
}

__global__ void cls_k(const float* __restrict__ cls_tok, const float* __restrict__ pos, u16* __restrict__ tok) {
  int b = blockIdx.x, d = threadIdx.x;
  tok[((size_t)b*197)*DD + d] = f2b(cls_tok[d] + pos[d]);
}

__global__ void fusew_k(const float* __restrict__ in_w, const float* __restrict__ q_w,
                        const float* __restrict__ k_w, const float* __restrict__ v_w,
                        u16* __restrict__ weff) {
  int i = blockIdx.x, p = blockIdx.y, n = blockIdx.z;
  int k = threadIdx.x;
  const float* wrow = in_w + ((size_t)i*576 + p*192 + n)*192;
  const float* Bm = (p==0 ? q_w : (p==1 ? k_w : v_w)) + (size_t)i*192*192;
  float acc = 0.f;
  for (int m=0;m<192;m++) acc += wrow[m] * Bm[m*192 + k];
  weff[((size_t)i*576 + p*192 + n)*192 + k] = f2b(acc);
}

__global__ void fuseb_k(const float* __restrict__ in_w, const float* __restrict__ q_b,
                        const float* __restrict__ k_b, const float* __restrict__ v_b,
                        const float* __restrict__ in_b, float* __restrict__ effb) {
  int i = blockIdx.x, n = threadIdx.x;
  int p = n / 192;
  const float* bb = (p==0 ? q_b : (p==1 ? k_b : v_b)) + i*192;
  const float* wrow = in_w + ((size_t)i*576 + n)*192;
  float acc = in_b[i*576 + n];
  for (int m=0;m<192;m++) acc += wrow[m]*bb[m];
  effb[i*576 + n] = acc;
}

// ---------- orchestration ----------
extern "C" void kernel_launch(void* const* d_in, const int* in_sizes, int n_in,
                              void* d_out, int out_size, void* d_ws, size_t ws_size,
                              hipStream_t stream) {
  const float* x      = (const float*)d_in[0];
  const float* lm_w   = (const float*)d_in[1];
  const float* lm_b   = (const float*)d_in[2];
  const float* cls_t  = (const float*)d_in[3];
  const float* pos    = (const float*)d_in[4];
  const float* q_w    = (const float*)d_in[5];
  const float* q_b    = (const float*)d_in[6];
  const float* k_w    = (const float*)d_in[7];
  const float* k_b    = (const float*)d_in[8];
  const float* v_w    = (const float*)d_in[9];
  const float* v_b    = (const float*)d_in[10];
  const float* in_w   = (const float*)d_in[11];
  const float* in_b   = (const float*)d_in[12];
  const float* out_w  = (const float*)d_in[13];
  const float* out_b  = (const float*)d_in[14];
  const float* up_w   = (const float*)d_in[15];
  const float* up_b   = (const float*)d_in[16];
  const float* dn_w   = (const float*)d_in[17];
  const float* dn_b   = (const float*)d_in[18];
  const float* head_w = (const float*)d_in[19];
  const float* head_b = (const float*)d_in[20];

  char* ws = (char*)d_ws;
  size_t off = 0;
  auto alloc = [&](size_t elems, size_t esz) {
    void* p = ws + off; off += ((elems*esz + 255)/256)*256; return p;
  };
  u16*  big  = (u16*)alloc(BIG_E, 2);        // patches / mlp hidden
  u16*  tok  = (u16*)alloc(TOK_E, 2);
  u16*  qq   = (u16*)alloc(QKV_E*3, 2);      // q,k,v contiguous (b,h,t,d) padded
  u16*  obuf = (u16*)alloc(TOK_E, 2);
  u16*  lmw  = (u16*)alloc(147456, 2);
  u16*  outw = (u16*)alloc(110592, 2);
  u16*  upw  = (u16*)alloc(442368, 2);
  u16*  dnw  = (u16*)alloc(442368, 2);
  u16*  hdw  = (u16*)alloc(196608, 2);
  u16*  weff = (u16*)alloc(331776, 2);
  float* effb = (float*)alloc(1728, 4);
  (void)ws_size; (void)in_sizes; (void)n_in; (void)out_size;

  u16* kbuf = qq + QKV_E;
  u16* vbuf = qq + 2*QKV_E;

  // weight prep (one launch) + QKV weight fusion
  cvt5_k<<<(1339392+255)/256,256,0,stream>>>(lm_w, out_w, up_w, dn_w, head_w,
                                             lmw, outw, upw, dnw, hdw);
  fusew_k<<<dim3(3,3,192),192,0,stream>>>(in_w, q_w, k_w, v_w, weff);
  fuseb_k<<<3,576,0,stream>>>(in_w, q_b, k_b, v_b, in_b, effb);

  // patch embed + pos + cls
  im2col_k<<<18816,256,0,stream>>>(x, big);
  gemm4w<M_PATCH,false,false,true><<<dim3(MPAT/256,3,1),256,0,stream>>>(
      big, lmw, lm_b, nullptr, tok, pos, 768, 768, DD, DD, 0,0,0);
  cls_k<<<BATCH,DD,0,stream>>>(cls_t, pos, tok);

  for (int i=0;i<3;i++) {
    gemm4w<M_QKV,false,false,true><<<dim3(MTOK/256,9,1),256,0,stream>>>(
        tok, weff + (size_t)i*576*192, effb + i*576, nullptr, qq, nullptr,
        192, 192, 0, 576, 0,0,0);
    flash_k<<<1024,256,0,stream>>>(qq, kbuf, vbuf, obuf);
    gemm4w<M_BF16,false,true,true><<<dim3(MTOK/256,3,1),256,0,stream>>>(
        obuf, outw + (size_t)i*36864, out_b + i*192, tok, tok, nullptr,
        192, 192, DD, DD, 0,0,0);
    gemm4w<M_BF16,true,false,true><<<dim3(MTOK/256,12,1),256,0,stream>>>(
        tok, upw + (size_t)i*147456, up_b + i*768, nullptr, big, nullptr,
        192, 192, 768, 768, 0,0,0);
    gemm4w<M_BF16,false,false,true><<<dim3(MTOK/256,3,1),256,0,stream>>>(
        big, dnw + (size_t)i*147456, dn_b + i*192, nullptr, tok, nullptr,
        768, 768, DD, DD, 0,0,0);
  }
  gemm4w<M_F32,false,false,true><<<dim3(1,16,1),256,0,stream>>>(
      tok, hdw, head_b, nullptr, d_out, nullptr,
      192, 197*192, 1000, 1000, 0,0,0);
}

// Round 4
// 987.618 us; speedup vs baseline: 1.2666x; 1.2666x over previous
//
#include <hip/hip_runtime.h>

typedef unsigned short u16;
typedef __bf16 bf16x8 __attribute__((ext_vector_type(8)));
typedef float  f32x4  __attribute__((ext_vector_type(4)));
typedef u16    u16x8  __attribute__((ext_vector_type(8)));

// ---------- problem constants ----------
#define BATCH 256
#define TT    197          // tokens
#define TP    256          // padded tokens
#define DD    192          // model dim
#define DHP   64           // padded head dim (real 48)
#define MTOK  (BATCH*TT)   // 50432 rows = 197*256
#define MPAT  (BATCH*196)  // 50176 rows

constexpr size_t BIG_E  = 1024ull*256*256;   // patches 38.5M / mlp-h 38.7M
constexpr size_t TOK_E  = (size_t)MTOK*DD;
constexpr size_t QKV_E  = 1024ull*TP*DHP;    // per q/k/v tensor (padded)

__device__ __forceinline__ float b2f(u16 h){ union{unsigned u; float f;} x; x.u=(unsigned)h<<16; return x.f; }
__device__ __forceinline__ u16 f2b(float f){ union{float f; unsigned u;} x{f}; unsigned r = x.u + 0x7fffu + ((x.u>>16)&1u); return (u16)(r>>16); }
__device__ __forceinline__ bf16x8 as_bf(u16x8 v){ return __builtin_bit_cast(bf16x8, v); }

__device__ __forceinline__ void gload_lds16(const void* g, void* l) {
  __builtin_amdgcn_global_load_lds((__attribute__((address_space(1))) void*)(size_t)g,
                                   (__attribute__((address_space(3))) void*)l, 16, 0, 0);
}

// ---------- 4-wave 256x64-tile MFMA GEMM:  C = A(MxK) @ W(NxK)^T ----------
// Double-buffered staging with COUNTED vmcnt (T3/T4), plus XCD-chunked tile
// swizzle (T1/m204): grid is (nN, nM); each XCD gets a contiguous run of
// m-tiles, iterating all n-tiles of an m-tile consecutively -> A-tile stays
// in that XCD's L2 across n-tiles instead of being re-fetched from HBM.
enum { M_F32=0, M_BF16=1, M_QKV=2, M_PATCH=4 };

template<int MODE, bool RELU, bool RES, bool BIAS>
__global__ __launch_bounds__(256)
void gemm4w(const u16* __restrict__ A, const u16* __restrict__ W,
            const float* __restrict__ bias, const u16* __restrict__ res,
            void* __restrict__ Cout, const float* __restrict__ aux,
            int K, int lda, int ldc, int Nreal,
            long bA, long bW, long bC)
{
  __shared__ __align__(16) u16 As[2][256*32];   // 32 KB (double-buffered)
  __shared__ __align__(16) u16 Ws[2][64*32];    // 8 KB
  const int tid  = threadIdx.x;
  const int wv   = tid >> 6;
  const int lane = tid & 63;

  // --- XCD-chunked bijective tile remap (pure permutation; z unused==0) ---
  const int nN  = gridDim.x, nM = gridDim.y;
  const int nwg = nN * nM;
  const int fid = blockIdx.x + nN * blockIdx.y;
  const int xcd = fid & 7, loc = fid >> 3;
  const int q8  = nwg >> 3, r8 = nwg & 7;
  const int tile = (xcd < r8 ? xcd * (q8 + 1) : r8 * (q8 + 1) + (xcd - r8) * q8) + loc;
  const int m0 = (tile / nN) * 256;
  const int n0 = (tile % nN) * 64;

  const int bz = blockIdx.z;
  const u16* Ab = A + (size_t)bz * (size_t)bA;
  const u16* Wb = W + (size_t)bz * (size_t)bW;

  const int lrow = lane & 15, quad = lane >> 4;
  const int srow = lane >> 2, sseg = lane & 3;

  f32x4 acc[4][4];
  #pragma unroll
  for (int i=0;i<4;i++)
    #pragma unroll
    for (int j=0;j<4;j++) { f32x4 z = {0.f,0.f,0.f,0.f}; acc[i][j] = z; }

  auto stage = [&](int bufi, int k0) {
    #pragma unroll
    for (int i=0;i<4;i++) {
      const u16* ga = Ab + (size_t)(m0 + i*64 + wv*16 + srow)*lda + (k0 + sseg*8);
      gload_lds16(ga, &As[bufi][(i*64 + wv*16)*32]);
    }
    const u16* gw = Wb + (size_t)(n0 + wv*16 + srow)*K + (k0 + sseg*8);
    gload_lds16(gw, &Ws[bufi][(wv*16)*32]);
  };

  const int nt = K >> 5;
  stage(0, 0);                       // prologue: tile 0 in flight (5 loads)
  int cur = 0;
  for (int t = 0; t < nt; ++t) {
    if (t + 1 < nt) {
      stage(cur ^ 1, (t + 1) << 5);  // issue next tile (now 10 in flight)
      asm volatile("s_waitcnt vmcnt(5)" ::: "memory");   // tile t done; t+1 stays in flight
    } else {
      asm volatile("s_waitcnt vmcnt(0)" ::: "memory");   // last tile: drain
    }
    asm volatile("s_barrier" ::: "memory");              // all waves' tile-t loads visible

    bf16x8 af[4], wf[4];
    #pragma unroll
    for (int i=0;i<4;i++) {
      af[i] = *(const bf16x8*)&As[cur][(wv*64 + i*16 + lrow)*32 + quad*8];
      wf[i] = *(const bf16x8*)&Ws[cur][(i*16 + lrow)*32 + quad*8];
    }
    #pragma unroll
    for (int mi=0;mi<4;mi++)
      #pragma unroll
      for (int ni=0;ni<4;ni++)
        acc[mi][ni] = __builtin_amdgcn_mfma_f32_16x16x32_bf16(af[mi], wf[ni], acc[mi][ni], 0,0,0);

    asm volatile("s_waitcnt lgkmcnt(0)" ::: "memory");   // my ds_reads of buf[cur] done
    asm volatile("s_barrier" ::: "memory");              // everyone done before overwrite
    cur ^= 1;
  }

  #pragma unroll
  for (int mi=0;mi<4;mi++) {
    #pragma unroll
    for (int ni=0;ni<4;ni++) {
      #pragma unroll
      for (int r=0;r<4;r++) {
        int row = m0 + wv*64 + mi*16 + quad*4 + r;
        int col = n0 + ni*16 + lrow;
        float v = acc[mi][ni][r];
        if constexpr (MODE == M_F32) {
          if (col < Nreal) {
            if constexpr (BIAS) v += bias[col];
            ((float*)Cout)[(size_t)row*ldc + col] = v;
          }
        } else if constexpr (MODE == M_BF16) {
          if constexpr (BIAS) v += bias[col];
          if constexpr (RES)  v += b2f(res[(size_t)row*ldc + col]);
          if constexpr (RELU) v = v > 0.f ? v : 0.f;
          ((u16*)Cout)[(size_t)bz*(size_t)bC + (size_t)row*ldc + col] = f2b(v);
        } else if constexpr (MODE == M_QKV) {
          v += bias[col];
          int sel = col / 192, rem = col % 192;
          int h = rem / 48, d = rem % 48;
          int b = row / 197, t = row % 197;
          ((u16*)Cout)[(size_t)sel*QKV_E + ((size_t)(b*4 + h)*TP + t)*DHP + d] = f2b(v);
        } else if constexpr (MODE == M_PATCH) {
          int b = row / 196, p = row % 196;
          v += bias[col] + aux[(size_t)(1 + p)*DD + col];
          ((u16*)Cout)[((size_t)(b*197) + 1 + p)*DD + col] = f2b(v);
        }
      }
    }
  }
}

// ---------- fused flash attention: one workgroup per (b,h) ----------
// LDS: K 208x72 (d-pad zeroed), Vt 49x216, P 4x16x72. 60.3 KB total.
#define KSTR 72
#define VSTR 216
#define PSTR 72
#define TKR  208

__global__ __launch_bounds__(256,1)
void flash_k(const u16* __restrict__ Qg, const u16* __restrict__ Kg,
             const u16* __restrict__ Vg, u16* __restrict__ Og)
{
  __shared__ __align__(16) u16 Ks[TKR*KSTR];
  __shared__ __align__(16) u16 Vs[49*VSTR];
  __shared__ __align__(16) u16 Ps[4*16*PSTR];
  const int bh = blockIdx.x;
  const int b = bh >> 2, h = bh & 3;
  const int tid = threadIdx.x, wv = tid >> 6, lane = tid & 63;
  const int lrow = lane & 15, quad = lane >> 4;
  const size_t base = (size_t)bh * TP * DHP;
  const float scale = 0.14433756729740643f;   // 1/sqrt(48)

  // Q fragments (A-layout): t = wv*64 + rg*16 + lrow, k(d) = ka*32 + quad*8
  bf16x8 qf[4][2];
  #pragma unroll
  for (int rg=0; rg<4; rg++)
    #pragma unroll
    for (int ka=0; ka<2; ka++)
      qf[rg][ka] = as_bf(*(const u16x8*)(Qg + base + (size_t)(wv*64+rg*16+lrow)*DHP + ka*32 + quad*8));

  // stage K rows 0..207: segs 0..5 = data, segs 6..7 = zeros (d pad)
  for (int it=0; it<5; it++) {
    int slot = it*256 + tid;
    if (slot < 1248) {
      int t = slot/6, sg = slot - t*6;
      u16x8 v = *(const u16x8*)(Kg + base + (size_t)t*DHP + sg*8);
      *(u16x8*)&Ks[t*KSTR + sg*8] = v;
    }
  }
  {
    u16x8 z = {0,0,0,0,0,0,0,0};
    for (int it=0; it<2; it++) {
      int slot = it*256 + tid;
      if (slot < 416) { int t = slot>>1, sg = 6 + (slot&1);
        *(u16x8*)&Ks[t*KSTR + sg*8] = z; }
    }
  }
  // stage V transposed: Vs[d][t], d<48, t<208
  for (int it=0; it<5; it++) {
    int slot = it*256 + tid;
    if (slot < 1248) {
      int sg = slot/208, t = slot - sg*208;
      u16x8 v = *(const u16x8*)(Vg + base + (size_t)t*DHP + sg*8);
      #pragma unroll
      for (int j=0;j<8;j++) Vs[(sg*8+j)*VSTR + t] = v[j];
    }
  }
  __syncthreads();

  f32x4 o[4][3];
  float m_i[4][4], l_i[4][4];
  #pragma unroll
  for (int rg=0;rg<4;rg++) {
    #pragma unroll
    for (int dg=0;dg<3;dg++) { f32x4 z = {0.f,0.f,0.f,0.f}; o[rg][dg] = z; }
    #pragma unroll
    for (int r=0;r<4;r++) { m_i[rg][r] = -1e30f; l_i[rg][r] = 0.f; }
  }
  u16* Pw = &Ps[wv*16*PSTR];

  #pragma unroll
  for (int c=0; c<4; c++) {
    const int NC = (c<3) ? 4 : 1;     // chunk 3: only cols 192..207 can be valid
    f32x4 s[4][4];
    #pragma unroll
    for (int rg=0;rg<4;rg++)
      #pragma unroll
      for (int cg=0;cg<4;cg++) if (cg < NC) { f32x4 z = {0.f,0.f,0.f,0.f}; s[rg][cg] = z; }

    // S chunk = Q @ K^T
    #pragma unroll
    for (int cg=0;cg<4;cg++) if (cg < NC) {
      #pragma unroll
      for (int ka=0; ka<2; ka++) {
        bf16x8 kf = as_bf(*(const u16x8*)&Ks[(c*64+cg*16+lrow)*KSTR + ka*32 + quad*8]);
        #pragma unroll
        for (int rg=0;rg<4;rg++)
          s[rg][cg] = __builtin_amdgcn_mfma_f32_16x16x32_bf16(qf[rg][ka], kf, s[rg][cg], 0,0,0);
      }
    }

    // online softmax + PV, per row-group
    #pragma unroll
    for (int rg=0;rg<4;rg++) {
      if (c == 3) {
        #pragma unroll
        for (int r=0;r<4;r++) s[rg][0][r] = (lrow >= 5) ? -1e30f : s[rg][0][r];
      }
      float mnew[4], al[4];
      #pragma unroll
      for (int r=0;r<4;r++) {
        float mc = s[rg][0][r];
        #pragma unroll
        for (int cg=1;cg<4;cg++) if (cg < NC) mc = fmaxf(mc, s[rg][cg][r]);
        #pragma unroll
        for (int sh=1; sh<16; sh<<=1) mc = fmaxf(mc, __shfl_xor(mc, sh, 64));
        float mo = m_i[rg][r];
        float mn = fmaxf(mo, mc);
        mnew[r] = mn;
        al[r] = __expf((mo - mn)*scale);
      }
      #pragma unroll
      for (int r=0;r<4;r++) {
        float acc = 0.f;
        #pragma unroll
        for (int cg=0;cg<4;cg++) if (cg < NC) {
          float p = __expf((s[rg][cg][r] - mnew[r])*scale);
          s[rg][cg][r] = p;
          acc += p;
        }
        #pragma unroll
        for (int sh=1; sh<16; sh<<=1) acc += __shfl_xor(acc, sh, 64);
        l_i[rg][r] = l_i[rg][r]*al[r] + acc;
        m_i[rg][r] = mnew[r];
      }
      #pragma unroll
      for (int dg=0;dg<3;dg++)
        #pragma unroll
        for (int r=0;r<4;r++) o[rg][dg][r] *= al[r];

      // P (C-layout) -> LDS (row-major) for A-layout reads
      #pragma unroll
      for (int cg=0;cg<4;cg++) if (cg < NC) {
        #pragma unroll
        for (int r=0;r<4;r++)
          Pw[(quad*4+r)*PSTR + cg*16 + lrow] = f2b(s[rg][cg][r]);
      }
      if (c == 3) {
        #pragma unroll
        for (int r=0;r<4;r++) Pw[(quad*4+r)*PSTR + 16 + lrow] = 0;
      }
      __builtin_amdgcn_s_waitcnt(0xC07F);   // lgkmcnt(0)

      const int NK = (c<3) ? 2 : 1;
      #pragma unroll
      for (int ka=0; ka<2; ka++) if (ka < NK) {
        bf16x8 pf = as_bf(*(const u16x8*)&Pw[lrow*PSTR + ka*32 + quad*8]);
        #pragma unroll
        for (int dg=0;dg<3;dg++) {
          bf16x8 vf = as_bf(*(const u16x8*)&Vs[(dg*16+lrow)*VSTR + c*64 + ka*32 + quad*8]);
          o[rg][dg] = __builtin_amdgcn_mfma_f32_16x16x32_bf16(pf, vf, o[rg][dg], 0,0,0);
        }
      }
      __builtin_amdgcn_s_waitcnt(0xC07F);   // drain reads before next rg overwrites Pw
    }
  }

  // epilogue: O /= l, store rows t<197, cols d<48
  #pragma unroll
  for (int rg=0;rg<4;rg++) {
    #pragma unroll
    for (int r=0;r<4;r++) {
      int t = wv*64 + rg*16 + quad*4 + r;
      if (t < 197) {
        float inv = 1.0f / l_i[rg][r];
        u16* dst = Og + ((size_t)(b*197) + t)*DD + h*48;
        #pragma unroll
        for (int dg=0;dg<3;dg++) dst[dg*16 + lrow] = f2b(o[rg][dg][r]*inv);
      }
    }
  }
}

// ---------- small kernels ----------
// all weight fp32->bf16 conversions in one launch (incl. head pad-to-zero)
__global__ void cvt5_k(const float* __restrict__ a, const float* __restrict__ b,
                       const float* __restrict__ c, const float* __restrict__ d,
                       const float* __restrict__ e,
                       u16* __restrict__ oa, u16* __restrict__ ob, u16* __restrict__ oc,
                       u16* __restrict__ od, u16* __restrict__ oe) {
  int i = blockIdx.x*256 + threadIdx.x;
  if (i < 147456) { oa[i] = f2b(a[i]); return; } i -= 147456;
  if (i < 110592) { ob[i] = f2b(b[i]); return; } i -= 110592;
  if (i < 442368) { oc[i] = f2b(c[i]); return; } i -= 442368;
  if (i < 442368) { od[i] = f2b(d[i]); return; } i -= 442368;
  if (i < 196608) { oe[i] = (i < 192000) ? f2b(e[i]) : (u16)0; }
}

__global__ void im2col_k(const float* __restrict__ x, u16* __restrict__ P) {
  int id = blockIdx.x*256 + threadIdx.x;
  int w8 = id % 28; int r = id / 28;
  int h  = r % 224; r /= 224;
  int c  = r % 3;   int b = r / 3;
  const float* src = x + (((size_t)(b*3 + c)*224 + h)*224 + w8*8);
  float4 a  = *(const float4*)src;
  float4 bb = *(const float4*)(src + 4);
  int pr = h >> 4, i = h & 15, pc = (w8*8) >> 4, j0 = (w8*8) & 15;
  u16* dst = P + ((size_t)(b*196) + pr*14 + pc)*768 + (c*256 + i*16 + j0);
  u16x8 o;
  o[0]=f2b(a.x); o[1]=f2b(a.y); o[2]=f2b(a.z); o[3]=f2b(a.w);
  o[4]=f2b(bb.x); o[5]=f2b(bb.y); o[6]=f2b(bb.z); o[7]=f2b(bb.w);
  *(u16x8*)dst = o;
}

__global__ void cls_k(const float* __restrict__ cls_tok, const float* __restrict__ pos, u16* __restrict__ tok) {
  int b = blockIdx.x, d = threadIdx.x;
  tok[((size_t)b*197)*DD + d] = f2b(cls_tok[d] + pos[d]);
}

__global__ void fusew_k(const float* __restrict__ in_w, const float* __restrict__ q_w,
                        const float* __restrict__ k_w, const float* __restrict__ v_w,
                        u16* __restrict__ weff) {
  int i = blockIdx.x, p = blockIdx.y, n = blockIdx.z;
  int k = threadIdx.x;
  const float* wrow = in_w + ((size_t)i*576 + p*192 + n)*192;
  const float* Bm = (p==0 ? q_w : (p==1 ? k_w : v_w)) + (size_t)i*192*192;
  float acc = 0.f;
  for (int m=0;m<192;m++) acc += wrow[m] * Bm[m*192 + k];
  weff[((size_t)i*576 + p*192 + n)*192 + k] = f2b(acc);
}

__global__ void fuseb_k(const float* __restrict__ in_w, const float* __restrict__ q_b,
                        const float* __restrict__ k_b, const float* __restrict__ v_b,
                        const float* __restrict__ in_b, float* __restrict__ effb) {
  int i = blockIdx.x, n = threadIdx.x;
  int p = n / 192;
  const float* bb = (p==0 ? q_b : (p==1 ? k_b : v_b)) + i*192;
  const float* wrow = in_w + ((size_t)i*576 + n)*192;
  float acc = in_b[i*576 + n];
  for (int m=0;m<192;m++) acc += wrow[m]*bb[m];
  effb[i*576 + n] = acc;
}

// ---------- orchestration ----------
extern "C" void kernel_launch(void* const* d_in, const int* in_sizes, int n_in,
                              void* d_out, int out_size, void* d_ws, size_t ws_size,
                              hipStream_t stream) {
  const float* x      = (const float*)d_in[0];
  const float* lm_w   = (const float*)d_in[1];
  const float* lm_b   = (const float*)d_in[2];
  const float* cls_t  = (const float*)d_in[3];
  const float* pos    = (const float*)d_in[4];
  const float* q_w    = (const float*)d_in[5];
  const float* q_b    = (const float*)d_in[6];
  const float* k_w    = (const float*)d_in[7];
  const float* k_b    = (const float*)d_in[8];
  const float* v_w    = (const float*)d_in[9];
  const float* v_b    = (const float*)d_in[10];
  const float* in_w   = (const float*)d_in[11];
  const float* in_b   = (const float*)d_in[12];
  const float* out_w  = (const float*)d_in[13];
  const float* out_b  = (const float*)d_in[14];
  const float* up_w   = (const float*)d_in[15];
  const float* up_b   = (const float*)d_in[16];
  const float* dn_w   = (const float*)d_in[17];
  const float* dn_b   = (const float*)d_in[18];
  const float* head_w = (const float*)d_in[19];
  const float* head_b = (const float*)d_in[20];

  char* ws = (char*)d_ws;
  size_t off = 0;
  auto alloc = [&](size_t elems, size_t esz) {
    void* p = ws + off; off += ((elems*esz + 255)/256)*256; return p;
  };
  u16*  big  = (u16*)alloc(BIG_E, 2);        // patches / mlp hidden
  u16*  tok  = (u16*)alloc(TOK_E, 2);
  u16*  qq   = (u16*)alloc(QKV_E*3, 2);      // q,k,v contiguous (b,h,t,d) padded
  u16*  obuf = (u16*)alloc(TOK_E, 2);
  u16*  lmw  = (u16*)alloc(147456, 2);
  u16*  outw = (u16*)alloc(110592, 2);
  u16*  upw  = (u16*)alloc(442368, 2);
  u16*  dnw  = (u16*)alloc(442368, 2);
  u16*  hdw  = (u16*)alloc(196608, 2);
  u16*  weff = (u16*)alloc(331776, 2);
  float* effb = (float*)alloc(1728, 4);
  (void)ws_size; (void)in_sizes; (void)n_in; (void)out_size;

  u16* kbuf = qq + QKV_E;
  u16* vbuf = qq + 2*QKV_E;

  // weight prep (one launch) + QKV weight fusion
  cvt5_k<<<(1339392+255)/256,256,0,stream>>>(lm_w, out_w, up_w, dn_w, head_w,
                                             lmw, outw, upw, dnw, hdw);
  fusew_k<<<dim3(3,3,192),192,0,stream>>>(in_w, q_w, k_w, v_w, weff);
  fuseb_k<<<3,576,0,stream>>>(in_w, q_b, k_b, v_b, in_b, effb);

  // patch embed + pos + cls   (grids are (nN, nM) for the XCD swizzle)
  im2col_k<<<18816,256,0,stream>>>(x, big);
  gemm4w<M_PATCH,false,false,true><<<dim3(3,MPAT/256,1),256,0,stream>>>(
      big, lmw, lm_b, nullptr, tok, pos, 768, 768, DD, DD, 0,0,0);
  cls_k<<<BATCH,DD,0,stream>>>(cls_t, pos, tok);

  for (int i=0;i<3;i++) {
    gemm4w<M_QKV,false,false,true><<<dim3(9,MTOK/256,1),256,0,stream>>>(
        tok, weff + (size_t)i*576*192, effb + i*576, nullptr, qq, nullptr,
        192, 192, 0, 576, 0,0,0);
    flash_k<<<1024,256,0,stream>>>(qq, kbuf, vbuf, obuf);
    gemm4w<M_BF16,false,true,true><<<dim3(3,MTOK/256,1),256,0,stream>>>(
        obuf, outw + (size_t)i*36864, out_b + i*192, tok, tok, nullptr,
        192, 192, DD, DD, 0,0,0);
    gemm4w<M_BF16,true,false,true><<<dim3(12,MTOK/256,1),256,0,stream>>>(
        tok, upw + (size_t)i*147456, up_b + i*768, nullptr, big, nullptr,
        192, 192, 768, 768, 0,0,0);
    gemm4w<M_BF16,false,false,true><<<dim3(3,MTOK/256,1),256,0,stream>>>(
        big, dnw + (size_t)i*147456, dn_b + i*192, nullptr, tok, nullptr,
        768, 768, DD, DD, 0,0,0);
  }
  gemm4w<M_F32,false,false,true><<<dim3(16,1,1),256,0,stream>>>(
      tok, hdw, head_b, nullptr, d_out, nullptr,
      192, 197*192, 1000, 1000, 0,0,0);
}

// Round 5
// 981.545 us; speedup vs baseline: 1.2744x; 1.0062x over previous
//
#include <hip/hip_runtime.h>

typedef unsigned short u16;
typedef __bf16 bf16x8 __attribute__((ext_vector_type(8)));
typedef float  f32x4  __attribute__((ext_vector_type(4)));
typedef u16    u16x8  __attribute__((ext_vector_type(8)));

// ---------- problem constants ----------
#define BATCH 256
#define TT    197          // tokens
#define TP    256          // padded tokens
#define DD    192          // model dim
#define DHP   64           // padded head dim (real 48)
#define MTOK  (BATCH*TT)   // 50432 rows = 197*256
#define MPAT  (BATCH*196)  // 50176 rows

constexpr size_t BIG_E  = 1024ull*256*256;   // patches 38.5M / mlp-h 38.7M
constexpr size_t TOK_E  = (size_t)MTOK*DD;
constexpr size_t QKV_E  = 1024ull*TP*DHP;    // per q/k/v tensor (padded)

__device__ __forceinline__ float b2f(u16 h){ union{unsigned u; float f;} x; x.u=(unsigned)h<<16; return x.f; }
__device__ __forceinline__ u16 f2b(float f){ union{float f; unsigned u;} x{f}; unsigned r = x.u + 0x7fffu + ((x.u>>16)&1u); return (u16)(r>>16); }
__device__ __forceinline__ bf16x8 as_bf(u16x8 v){ return __builtin_bit_cast(bf16x8, v); }

__device__ __forceinline__ void gload_lds16(const void* g, void* l) {
  __builtin_amdgcn_global_load_lds((__attribute__((address_space(1))) void*)(size_t)g,
                                   (__attribute__((address_space(3))) void*)l, 16, 0, 0);
}

// ---------- 4-wave 256x64-tile MFMA GEMM:  C = A(MxK) @ W(NxK)^T ----------
// Double-buffered staging, counted vmcnt (T3/T4), XCD-chunked tile swizzle
// (T1/m204), and T2 LDS de-conflict: rows are 64B, so a naive ds_read_b128 at
// row*64+quad*16 is ~8-way bank-conflicted (even rows all on banks 0-3).
// Fix per rule #21 (gload_lds writes linearly): pre-swizzle the GLOBAL source
// chunk (sseg ^ ((srow>>1)&3)) and read with the same XOR -> 2-way (free).
enum { M_F32=0, M_BF16=1, M_QKV=2, M_PATCH=4 };

template<int MODE, bool RELU, bool RES, bool BIAS>
__global__ __launch_bounds__(256)
void gemm4w(const u16* __restrict__ A, const u16* __restrict__ W,
            const float* __restrict__ bias, const u16* __restrict__ res,
            void* __restrict__ Cout, const float* __restrict__ aux,
            int K, int lda, int ldc, int Nreal,
            long bA, long bW, long bC)
{
  __shared__ __align__(16) u16 As[2][256*32];   // 32 KB (double-buffered)
  __shared__ __align__(16) u16 Ws[2][64*32];    // 8 KB
  const int tid  = threadIdx.x;
  const int wv   = tid >> 6;
  const int lane = tid & 63;

  // --- XCD-chunked bijective tile remap (pure permutation; z unused==0) ---
  const int nN  = gridDim.x, nM = gridDim.y;
  const int nwg = nN * nM;
  const int fid = blockIdx.x + nN * blockIdx.y;
  const int xcd = fid & 7, loc = fid >> 3;
  const int q8  = nwg >> 3, r8 = nwg & 7;
  const int tile = (xcd < r8 ? xcd * (q8 + 1) : r8 * (q8 + 1) + (xcd - r8) * q8) + loc;
  const int m0 = (tile / nN) * 256;
  const int n0 = (tile % nN) * 64;

  const int bz = blockIdx.z;
  const u16* Ab = A + (size_t)bz * (size_t)bA;
  const u16* Wb = W + (size_t)bz * (size_t)bW;

  const int lrow = lane & 15, quad = lane >> 4;
  const int srow = lane >> 2, sseg = lane & 3;
  const int wsw  = (srow >> 1) & 3;            // write-side swizzle (global pre-swizzle)
  const int rsw  = (lrow >> 1) & 3;            // read-side swizzle (same XOR)

  f32x4 acc[4][4];
  #pragma unroll
  for (int i=0;i<4;i++)
    #pragma unroll
    for (int j=0;j<4;j++) { f32x4 z = {0.f,0.f,0.f,0.f}; acc[i][j] = z; }

  auto stage = [&](int bufi, int k0) {
    #pragma unroll
    for (int i=0;i<4;i++) {
      const u16* ga = Ab + (size_t)(m0 + i*64 + wv*16 + srow)*lda + (k0 + (sseg^wsw)*8);
      gload_lds16(ga, &As[bufi][(i*64 + wv*16)*32]);
    }
    const u16* gw = Wb + (size_t)(n0 + wv*16 + srow)*K + (k0 + (sseg^wsw)*8);
    gload_lds16(gw, &Ws[bufi][(wv*16)*32]);
  };

  const int nt = K >> 5;
  stage(0, 0);                       // prologue: tile 0 in flight (5 loads)
  int cur = 0;
  for (int t = 0; t < nt; ++t) {
    if (t + 1 < nt) {
      stage(cur ^ 1, (t + 1) << 5);  // issue next tile (now 10 in flight)
      asm volatile("s_waitcnt vmcnt(5)" ::: "memory");   // tile t done; t+1 stays in flight
    } else {
      asm volatile("s_waitcnt vmcnt(0)" ::: "memory");   // last tile: drain
    }
    asm volatile("s_barrier" ::: "memory");              // all waves' tile-t loads visible

    bf16x8 af[4], wf[4];
    #pragma unroll
    for (int i=0;i<4;i++) {
      af[i] = *(const bf16x8*)&As[cur][(wv*64 + i*16 + lrow)*32 + (quad^rsw)*8];
      wf[i] = *(const bf16x8*)&Ws[cur][(i*16 + lrow)*32 + (quad^rsw)*8];
    }
    #pragma unroll
    for (int mi=0;mi<4;mi++)
      #pragma unroll
      for (int ni=0;ni<4;ni++)
        acc[mi][ni] = __builtin_amdgcn_mfma_f32_16x16x32_bf16(af[mi], wf[ni], acc[mi][ni], 0,0,0);

    asm volatile("s_waitcnt lgkmcnt(0)" ::: "memory");   // my ds_reads of buf[cur] done
    asm volatile("s_barrier" ::: "memory");              // everyone done before overwrite
    cur ^= 1;
  }

  #pragma unroll
  for (int mi=0;mi<4;mi++) {
    #pragma unroll
    for (int ni=0;ni<4;ni++) {
      #pragma unroll
      for (int r=0;r<4;r++) {
        int row = m0 + wv*64 + mi*16 + quad*4 + r;
        int col = n0 + ni*16 + lrow;
        float v = acc[mi][ni][r];
        if constexpr (MODE == M_F32) {
          if (col < Nreal) {
            if constexpr (BIAS) v += bias[col];
            ((float*)Cout)[(size_t)row*ldc + col] = v;
          }
        } else if constexpr (MODE == M_BF16) {
          if constexpr (BIAS) v += bias[col];
          if constexpr (RES)  v += b2f(res[(size_t)row*ldc + col]);
          if constexpr (RELU) v = v > 0.f ? v : 0.f;
          ((u16*)Cout)[(size_t)bz*(size_t)bC + (size_t)row*ldc + col] = f2b(v);
        } else if constexpr (MODE == M_QKV) {
          v += bias[col];
          int sel = col / 192, rem = col % 192;
          int h = rem / 48, d = rem % 48;
          int b = row / 197, t = row % 197;
          ((u16*)Cout)[(size_t)sel*QKV_E + ((size_t)(b*4 + h)*TP + t)*DHP + d] = f2b(v);
        } else if constexpr (MODE == M_PATCH) {
          int b = row / 196, p = row % 196;
          v += bias[col] + aux[(size_t)(1 + p)*DD + col];
          ((u16*)Cout)[((size_t)(b*197) + 1 + p)*DD + col] = f2b(v);
        }
      }
    }
  }
}

// ---------- fused flash attention: one workgroup per (b,h) ----------
// LDS: K 208x72 (d-pad zeroed), Vt 49x216, P 4x16x72. 60.3 KB total.
#define KSTR 72
#define VSTR 216
#define PSTR 72
#define TKR  208

__global__ __launch_bounds__(256,1)
void flash_k(const u16* __restrict__ Qg, const u16* __restrict__ Kg,
             const u16* __restrict__ Vg, u16* __restrict__ Og)
{
  __shared__ __align__(16) u16 Ks[TKR*KSTR];
  __shared__ __align__(16) u16 Vs[49*VSTR];
  __shared__ __align__(16) u16 Ps[4*16*PSTR];
  const int bh = blockIdx.x;
  const int b = bh >> 2, h = bh & 3;
  const int tid = threadIdx.x, wv = tid >> 6, lane = tid & 63;
  const int lrow = lane & 15, quad = lane >> 4;
  const size_t base = (size_t)bh * TP * DHP;
  const float scale = 0.14433756729740643f;   // 1/sqrt(48)

  // Q fragments (A-layout): t = wv*64 + rg*16 + lrow, k(d) = ka*32 + quad*8
  bf16x8 qf[4][2];
  #pragma unroll
  for (int rg=0; rg<4; rg++)
    #pragma unroll
    for (int ka=0; ka<2; ka++)
      qf[rg][ka] = as_bf(*(const u16x8*)(Qg + base + (size_t)(wv*64+rg*16+lrow)*DHP + ka*32 + quad*8));

  // stage K rows 0..207: segs 0..5 = data, segs 6..7 = zeros (d pad)
  for (int it=0; it<5; it++) {
    int slot = it*256 + tid;
    if (slot < 1248) {
      int t = slot/6, sg = slot - t*6;
      u16x8 v = *(const u16x8*)(Kg + base + (size_t)t*DHP + sg*8);
      *(u16x8*)&Ks[t*KSTR + sg*8] = v;
    }
  }
  {
    u16x8 z = {0,0,0,0,0,0,0,0};
    for (int it=0; it<2; it++) {
      int slot = it*256 + tid;
      if (slot < 416) { int t = slot>>1, sg = 6 + (slot&1);
        *(u16x8*)&Ks[t*KSTR + sg*8] = z; }
    }
  }
  // stage V transposed: Vs[d][t], d<48, t<208
  for (int it=0; it<5; it++) {
    int slot = it*256 + tid;
    if (slot < 1248) {
      int sg = slot/208, t = slot - sg*208;
      u16x8 v = *(const u16x8*)(Vg + base + (size_t)t*DHP + sg*8);
      #pragma unroll
      for (int j=0;j<8;j++) Vs[(sg*8+j)*VSTR + t] = v[j];
    }
  }
  __syncthreads();

  f32x4 o[4][3];
  float m_i[4][4], l_i[4][4];
  #pragma unroll
  for (int rg=0;rg<4;rg++) {
    #pragma unroll
    for (int dg=0;dg<3;dg++) { f32x4 z = {0.f,0.f,0.f,0.f}; o[rg][dg] = z; }
    #pragma unroll
    for (int r=0;r<4;r++) { m_i[rg][r] = -1e30f; l_i[rg][r] = 0.f; }
  }
  u16* Pw = &Ps[wv*16*PSTR];

  #pragma unroll
  for (int c=0; c<4; c++) {
    const int NC = (c<3) ? 4 : 1;     // chunk 3: only cols 192..207 can be valid
    f32x4 s[4][4];
    #pragma unroll
    for (int rg=0;rg<4;rg++)
      #pragma unroll
      for (int cg=0;cg<4;cg++) if (cg < NC) { f32x4 z = {0.f,0.f,0.f,0.f}; s[rg][cg] = z; }

    // S chunk = Q @ K^T
    #pragma unroll
    for (int cg=0;cg<4;cg++) if (cg < NC) {
      #pragma unroll
      for (int ka=0; ka<2; ka++) {
        bf16x8 kf = as_bf(*(const u16x8*)&Ks[(c*64+cg*16+lrow)*KSTR + ka*32 + quad*8]);
        #pragma unroll
        for (int rg=0;rg<4;rg++)
          s[rg][cg] = __builtin_amdgcn_mfma_f32_16x16x32_bf16(qf[rg][ka], kf, s[rg][cg], 0,0,0);
      }
    }

    // online softmax + PV, per row-group
    #pragma unroll
    for (int rg=0;rg<4;rg++) {
      if (c == 3) {
        #pragma unroll
        for (int r=0;r<4;r++) s[rg][0][r] = (lrow >= 5) ? -1e30f : s[rg][0][r];
      }
      float mnew[4], al[4];
      #pragma unroll
      for (int r=0;r<4;r++) {
        float mc = s[rg][0][r];
        #pragma unroll
        for (int cg=1;cg<4;cg++) if (cg < NC) mc = fmaxf(mc, s[rg][cg][r]);
        #pragma unroll
        for (int sh=1; sh<16; sh<<=1) mc = fmaxf(mc, __shfl_xor(mc, sh, 64));
        float mo = m_i[rg][r];
        float mn = fmaxf(mo, mc);
        mnew[r] = mn;
        al[r] = __expf((mo - mn)*scale);
      }
      #pragma unroll
      for (int r=0;r<4;r++) {
        float acc = 0.f;
        #pragma unroll
        for (int cg=0;cg<4;cg++) if (cg < NC) {
          float p = __expf((s[rg][cg][r] - mnew[r])*scale);
          s[rg][cg][r] = p;
          acc += p;
        }
        #pragma unroll
        for (int sh=1; sh<16; sh<<=1) acc += __shfl_xor(acc, sh, 64);
        l_i[rg][r] = l_i[rg][r]*al[r] + acc;
        m_i[rg][r] = mnew[r];
      }
      #pragma unroll
      for (int dg=0;dg<3;dg++)
        #pragma unroll
        for (int r=0;r<4;r++) o[rg][dg][r] *= al[r];

      // P (C-layout) -> LDS (row-major) for A-layout reads
      #pragma unroll
      for (int cg=0;cg<4;cg++) if (cg < NC) {
        #pragma unroll
        for (int r=0;r<4;r++)
          Pw[(quad*4+r)*PSTR + cg*16 + lrow] = f2b(s[rg][cg][r]);
      }
      if (c == 3) {
        #pragma unroll
        for (int r=0;r<4;r++) Pw[(quad*4+r)*PSTR + 16 + lrow] = 0;
      }
      __builtin_amdgcn_s_waitcnt(0xC07F);   // lgkmcnt(0)

      const int NK = (c<3) ? 2 : 1;
      #pragma unroll
      for (int ka=0; ka<2; ka++) if (ka < NK) {
        bf16x8 pf = as_bf(*(const u16x8*)&Pw[lrow*PSTR + ka*32 + quad*8]);
        #pragma unroll
        for (int dg=0;dg<3;dg++) {
          bf16x8 vf = as_bf(*(const u16x8*)&Vs[(dg*16+lrow)*VSTR + c*64 + ka*32 + quad*8]);
          o[rg][dg] = __builtin_amdgcn_mfma_f32_16x16x32_bf16(pf, vf, o[rg][dg], 0,0,0);
        }
      }
      __builtin_amdgcn_s_waitcnt(0xC07F);   // drain reads before next rg overwrites Pw
    }
  }

  // epilogue: O /= l, store rows t<197, cols d<48
  #pragma unroll
  for (int rg=0;rg<4;rg++) {
    #pragma unroll
    for (int r=0;r<4;r++) {
      int t = wv*64 + rg*16 + quad*4 + r;
      if (t < 197) {
        float inv = 1.0f / l_i[rg][r];
        u16* dst = Og + ((size_t)(b*197) + t)*DD + h*48;
        #pragma unroll
        for (int dg=0;dg<3;dg++) dst[dg*16 + lrow] = f2b(o[rg][dg][r]*inv);
      }
    }
  }
}

// ---------- small kernels ----------
// all weight fp32->bf16 conversions in one launch (incl. head pad-to-zero)
__global__ void cvt5_k(const float* __restrict__ a, const float* __restrict__ b,
                       const float* __restrict__ c, const float* __restrict__ d,
                       const float* __restrict__ e,
                       u16* __restrict__ oa, u16* __restrict__ ob, u16* __restrict__ oc,
                       u16* __restrict__ od, u16* __restrict__ oe) {
  int i = blockIdx.x*256 + threadIdx.x;
  if (i < 147456) { oa[i] = f2b(a[i]); return; } i -= 147456;
  if (i < 110592) { ob[i] = f2b(b[i]); return; } i -= 110592;
  if (i < 442368) { oc[i] = f2b(c[i]); return; } i -= 442368;
  if (i < 442368) { od[i] = f2b(d[i]); return; } i -= 442368;
  if (i < 196608) { oe[i] = (i < 192000) ? f2b(e[i]) : (u16)0; }
}

__global__ void im2col_k(const float* __restrict__ x, u16* __restrict__ P) {
  int id = blockIdx.x*256 + threadIdx.x;
  int w8 = id % 28; int r = id / 28;
  int h  = r % 224; r /= 224;
  int c  = r % 3;   int b = r / 3;
  const float* src = x + (((size_t)(b*3 + c)*224 + h)*224 + w8*8);
  float4 a  = *(const float4*)src;
  float4 bb = *(const float4*)(src + 4);
  int pr = h >> 4, i = h & 15, pc = (w8*8) >> 4, j0 = (w8*8) & 15;
  u16* dst = P + ((size_t)(b*196) + pr*14 + pc)*768 + (c*256 + i*16 + j0);
  u16x8 o;
  o[0]=f2b(a.x); o[1]=f2b(a.y); o[2]=f2b(a.z); o[3]=f2b(a.w);
  o[4]=f2b(bb.x); o[5]=f2b(bb.y); o[6]=f2b(bb.z); o[7]=f2b(bb.w);
  *(u16x8*)dst = o;
}

__global__ void cls_k(const float* __restrict__ cls_tok, const float* __restrict__ pos, u16* __restrict__ tok) {
  int b = blockIdx.x, d = threadIdx.x;
  tok[((size_t)b*197)*DD + d] = f2b(cls_tok[d] + pos[d]);
}

__global__ void fusew_k(const float* __restrict__ in_w, const float* __restrict__ q_w,
                        const float* __restrict__ k_w, const float* __restrict__ v_w,
                        u16* __restrict__ weff) {
  int i = blockIdx.x, p = blockIdx.y, n = blockIdx.z;
  int k = threadIdx.x;
  const float* wrow = in_w + ((size_t)i*576 + p*192 + n)*192;
  const float* Bm = (p==0 ? q_w : (p==1 ? k_w : v_w)) + (size_t)i*192*192;
  float acc = 0.f;
  for (int m=0;m<192;m++) acc += wrow[m] * Bm[m*192 + k];
  weff[((size_t)i*576 + p*192 + n)*192 + k] = f2b(acc);
}

__global__ void fuseb_k(const float* __restrict__ in_w, const float* __restrict__ q_b,
                        const float* __restrict__ k_b, const float* __restrict__ v_b,
                        const float* __restrict__ in_b, float* __restrict__ effb) {
  int i = blockIdx.x, n = threadIdx.x;
  int p = n / 192;
  const float* bb = (p==0 ? q_b : (p==1 ? k_b : v_b)) + i*192;
  const float* wrow = in_w + ((size_t)i*576 + n)*192;
  float acc = in_b[i*576 + n];
  for (int m=0;m<192;m++) acc += wrow[m]*bb[m];
  effb[i*576 + n] = acc;
}

// ---------- orchestration ----------
extern "C" void kernel_launch(void* const* d_in, const int* in_sizes, int n_in,
                              void* d_out, int out_size, void* d_ws, size_t ws_size,
                              hipStream_t stream) {
  const float* x      = (const float*)d_in[0];
  const float* lm_w   = (const float*)d_in[1];
  const float* lm_b   = (const float*)d_in[2];
  const float* cls_t  = (const float*)d_in[3];
  const float* pos    = (const float*)d_in[4];
  const float* q_w    = (const float*)d_in[5];
  const float* q_b    = (const float*)d_in[6];
  const float* k_w    = (const float*)d_in[7];
  const float* k_b    = (const float*)d_in[8];
  const float* v_w    = (const float*)d_in[9];
  const float* v_b    = (const float*)d_in[10];
  const float* in_w   = (const float*)d_in[11];
  const float* in_b   = (const float*)d_in[12];
  const float* out_w  = (const float*)d_in[13];
  const float* out_b  = (const float*)d_in[14];
  const float* up_w   = (const float*)d_in[15];
  const float* up_b   = (const float*)d_in[16];
  const float* dn_w   = (const float*)d_in[17];
  const float* dn_b   = (const float*)d_in[18];
  const float* head_w = (const float*)d_in[19];
  const float* head_b = (const float*)d_in[20];

  char* ws = (char*)d_ws;
  size_t off = 0;
  auto alloc = [&](size_t elems, size_t esz) {
    void* p = ws + off; off += ((elems*esz + 255)/256)*256; return p;
  };
  u16*  big  = (u16*)alloc(BIG_E, 2);        // patches / mlp hidden
  u16*  tok  = (u16*)alloc(TOK_E, 2);
  u16*  qq   = (u16*)alloc(QKV_E*3, 2);      // q,k,v contiguous (b,h,t,d) padded
  u16*  obuf = (u16*)alloc(TOK_E, 2);
  u16*  lmw  = (u16*)alloc(147456, 2);
  u16*  outw = (u16*)alloc(110592, 2);
  u16*  upw  = (u16*)alloc(442368, 2);
  u16*  dnw  = (u16*)alloc(442368, 2);
  u16*  hdw  = (u16*)alloc(196608, 2);
  u16*  weff = (u16*)alloc(331776, 2);
  float* effb = (float*)alloc(1728, 4);
  (void)ws_size; (void)in_sizes; (void)n_in; (void)out_size;

  u16* kbuf = qq + QKV_E;
  u16* vbuf = qq + 2*QKV_E;

  // weight prep (one launch) + QKV weight fusion
  cvt5_k<<<(1339392+255)/256,256,0,stream>>>(lm_w, out_w, up_w, dn_w, head_w,
                                             lmw, outw, upw, dnw, hdw);
  fusew_k<<<dim3(3,3,192),192,0,stream>>>(in_w, q_w, k_w, v_w, weff);
  fuseb_k<<<3,576,0,stream>>>(in_w, q_b, k_b, v_b, in_b, effb);

  // patch embed + pos + cls   (grids are (nN, nM) for the XCD swizzle)
  im2col_k<<<18816,256,0,stream>>>(x, big);
  gemm4w<M_PATCH,false,false,true><<<dim3(3,MPAT/256,1),256,0,stream>>>(
      big, lmw, lm_b, nullptr, tok, pos, 768, 768, DD, DD, 0,0,0);
  cls_k<<<BATCH,DD,0,stream>>>(cls_t, pos, tok);

  for (int i=0;i<3;i++) {
    gemm4w<M_QKV,false,false,true><<<dim3(9,MTOK/256,1),256,0,stream>>>(
        tok, weff + (size_t)i*576*192, effb + i*576, nullptr, qq, nullptr,
        192, 192, 0, 576, 0,0,0);
    flash_k<<<1024,256,0,stream>>>(qq, kbuf, vbuf, obuf);
    gemm4w<M_BF16,false,true,true><<<dim3(3,MTOK/256,1),256,0,stream>>>(
        obuf, outw + (size_t)i*36864, out_b + i*192, tok, tok, nullptr,
        192, 192, DD, DD, 0,0,0);
    gemm4w<M_BF16,true,false,true><<<dim3(12,MTOK/256,1),256,0,stream>>>(
        tok, upw + (size_t)i*147456, up_b + i*768, nullptr, big, nullptr,
        192, 192, 768, 768, 0,0,0);
    gemm4w<M_BF16,false,false,true><<<dim3(3,MTOK/256,1),256,0,stream>>>(
        big, dnw + (size_t)i*147456, dn_b + i*192, nullptr, tok, nullptr,
        768, 768, DD, DD, 0,0,0);
  }
  gemm4w<M_F32,false,false,true><<<dim3(16,1,1),256,0,stream>>>(
      tok, hdw, head_b, nullptr, d_out, nullptr,
      192, 197*192, 1000, 1000, 0,0,0);
}

// Round 6
// 973.802 us; speedup vs baseline: 1.2846x; 1.0080x over previous
//
#include <hip/hip_runtime.h>

typedef unsigned short u16;
typedef __bf16 bf16x8 __attribute__((ext_vector_type(8)));
typedef float  f32x4  __attribute__((ext_vector_type(4)));
typedef u16    u16x8  __attribute__((ext_vector_type(8)));

// ---------- problem constants ----------
#define BATCH 256
#define TT    197          // tokens
#define TP    256          // padded tokens
#define DD    192          // model dim
#define DHP   64           // padded head dim (real 48)
#define MTOK  (BATCH*TT)   // 50432 rows = 197*256
#define MPAT  (BATCH*196)  // 50176 rows

constexpr size_t BIG_E  = 1024ull*256*256;   // patches 38.5M / mlp-h 38.7M
constexpr size_t TOK_E  = (size_t)MTOK*DD;
constexpr size_t QKV_E  = 1024ull*TP*DHP;    // per q/k/v tensor (padded)

__device__ __forceinline__ float b2f(u16 h){ union{unsigned u; float f;} x; x.u=(unsigned)h<<16; return x.f; }
__device__ __forceinline__ u16 f2b(float f){ union{float f; unsigned u;} x{f}; unsigned r = x.u + 0x7fffu + ((x.u>>16)&1u); return (u16)(r>>16); }
__device__ __forceinline__ bf16x8 as_bf(u16x8 v){ return __builtin_bit_cast(bf16x8, v); }

__device__ __forceinline__ void gload_lds16(const void* g, void* l) {
  __builtin_amdgcn_global_load_lds((__attribute__((address_space(1))) void*)(size_t)g,
                                   (__attribute__((address_space(3))) void*)l, 16, 0, 0);
}

// ---------- 4-wave 128x64-tile MFMA GEMM:  C = A(MxK) @ W(NxK)^T ----------
// 3-buffer, 2-deep prefetch, ONE barrier per K-step (T3/T4 deepened):
//   iter t: vmcnt(3) [tile t ready; t+1's 3 loads stay in flight] -> barrier
//           -> stage(t+2) -> ds_read/MFMA tile t.
// Hazards: buf[(t+2)%3] was last read at iter t-1; any wave past barrier(t)
// has issued its iter-(t-1) MFMAs => its ds_reads completed => restage safe.
// Loads get TWO compute phases (~2x) of latency cover vs the old 2-phase loop.
enum { M_F32=0, M_BF16=1, M_QKV=2, M_PATCH=4 };

template<int MODE, bool RELU, bool RES, bool BIAS>
__global__ __launch_bounds__(256)
void gemm4w(const u16* __restrict__ A, const u16* __restrict__ W,
            const float* __restrict__ bias, const u16* __restrict__ res,
            void* __restrict__ Cout, const float* __restrict__ aux,
            int K, int lda, int ldc, int Nreal,
            long bA, long bW, long bC)
{
  __shared__ __align__(16) u16 As[3][128*32];   // 24 KB
  __shared__ __align__(16) u16 Ws[3][64*32];    // 12 KB
  const int tid  = threadIdx.x;
  const int wv   = tid >> 6;
  const int lane = tid & 63;

  // --- XCD-chunked bijective tile remap (pure permutation; z unused==0) ---
  const int nN  = gridDim.x, nM = gridDim.y;
  const int nwg = nN * nM;
  const int fid = blockIdx.x + nN * blockIdx.y;
  const int xcd = fid & 7, loc = fid >> 3;
  const int q8  = nwg >> 3, r8 = nwg & 7;
  const int tile = (xcd < r8 ? xcd * (q8 + 1) : r8 * (q8 + 1) + (xcd - r8) * q8) + loc;
  const int m0 = (tile / nN) * 128;
  const int n0 = (tile % nN) * 64;

  const int bz = blockIdx.z;
  const u16* Ab = A + (size_t)bz * (size_t)bA;
  const u16* Wb = W + (size_t)bz * (size_t)bW;

  const int lrow = lane & 15, quad = lane >> 4;
  const int srow = lane >> 2, sseg = lane & 3;
  const int wsw  = (srow >> 1) & 3;            // write-side swizzle (global pre-swizzle)
  const int rsw  = (lrow >> 1) & 3;            // read-side swizzle (same XOR)

  f32x4 acc[2][4];
  #pragma unroll
  for (int i=0;i<2;i++)
    #pragma unroll
    for (int j=0;j<4;j++) { f32x4 z = {0.f,0.f,0.f,0.f}; acc[i][j] = z; }

  auto stage = [&](int bufi, int k0) {
    #pragma unroll
    for (int i=0;i<2;i++) {
      const u16* ga = Ab + (size_t)(m0 + i*64 + wv*16 + srow)*lda + (k0 + (sseg^wsw)*8);
      gload_lds16(ga, &As[bufi][(i*64 + wv*16)*32]);
    }
    const u16* gw = Wb + (size_t)(n0 + wv*16 + srow)*K + (k0 + (sseg^wsw)*8);
    gload_lds16(gw, &Ws[bufi][(wv*16)*32]);
  };

  const int nt = K >> 5;                // K >= 192 -> nt >= 6
  stage(0, 0);
  stage(1, 32);                         // 2 tiles in flight (6 loads)
  for (int t = 0; t < nt; ++t) {
    if (t + 1 < nt) {
      asm volatile("s_waitcnt vmcnt(3)" ::: "memory");   // tile t done; t+1 in flight
    } else {
      asm volatile("s_waitcnt vmcnt(0)" ::: "memory");   // last tile: drain
    }
    asm volatile("s_barrier" ::: "memory");              // tile-t writes visible to all
    if (t + 2 < nt) stage((t + 2) % 3, (t + 2) << 5);    // overlaps with compute below

    const int cur = t % 3;
    bf16x8 af[2], wf[4];
    #pragma unroll
    for (int i=0;i<2;i++)
      af[i] = *(const bf16x8*)&As[cur][(wv*32 + i*16 + lrow)*32 + (quad^rsw)*8];
    #pragma unroll
    for (int i=0;i<4;i++)
      wf[i] = *(const bf16x8*)&Ws[cur][(i*16 + lrow)*32 + (quad^rsw)*8];
    #pragma unroll
    for (int mi=0;mi<2;mi++)
      #pragma unroll
      for (int ni=0;ni<4;ni++)
        acc[mi][ni] = __builtin_amdgcn_mfma_f32_16x16x32_bf16(af[mi], wf[ni], acc[mi][ni], 0,0,0);
  }

  #pragma unroll
  for (int mi=0;mi<2;mi++) {
    #pragma unroll
    for (int ni=0;ni<4;ni++) {
      #pragma unroll
      for (int r=0;r<4;r++) {
        int row = m0 + wv*32 + mi*16 + quad*4 + r;
        int col = n0 + ni*16 + lrow;
        float v = acc[mi][ni][r];
        if constexpr (MODE == M_F32) {
          if (col < Nreal) {
            if constexpr (BIAS) v += bias[col];
            ((float*)Cout)[(size_t)row*ldc + col] = v;
          }
        } else if constexpr (MODE == M_BF16) {
          if constexpr (BIAS) v += bias[col];
          if constexpr (RES)  v += b2f(res[(size_t)row*ldc + col]);
          if constexpr (RELU) v = v > 0.f ? v : 0.f;
          ((u16*)Cout)[(size_t)bz*(size_t)bC + (size_t)row*ldc + col] = f2b(v);
        } else if constexpr (MODE == M_QKV) {
          v += bias[col];
          int sel = col / 192, rem = col % 192;
          int h = rem / 48, d = rem % 48;
          int b = row / 197, t = row % 197;
          ((u16*)Cout)[(size_t)sel*QKV_E + ((size_t)(b*4 + h)*TP + t)*DHP + d] = f2b(v);
        } else if constexpr (MODE == M_PATCH) {
          int b = row / 196, p = row % 196;
          v += bias[col] + aux[(size_t)(1 + p)*DD + col];
          ((u16*)Cout)[((size_t)(b*197) + 1 + p)*DD + col] = f2b(v);
        }
      }
    }
  }
}

// ---------- fused flash attention: one workgroup per (b,h) ----------
// LDS: K 208x72 (d-pad zeroed), Vt 49x216, P 2x(4x16x72) double-buffered.
// 69.5 KB total -> 2 blocks/CU. PV of iteration it-1 is DEFERRED into
// iteration it (T15): drain waits on writes issued a full softmax ago (free),
// and PV MFMAs overlap the next softmax's VALU/shuffle chain.
#define KSTR 72
#define VSTR 216
#define PSTR 72
#define TKR  208

__global__ __launch_bounds__(256,1)
void flash_k(const u16* __restrict__ Qg, const u16* __restrict__ Kg,
             const u16* __restrict__ Vg, u16* __restrict__ Og)
{
  __shared__ __align__(16) u16 Ks[TKR*KSTR];
  __shared__ __align__(16) u16 Vs[49*VSTR];
  __shared__ __align__(16) u16 Ps[8*16*PSTR];   // 2 banks x 4 waves
  const int bh = blockIdx.x;
  const int b = bh >> 2, h = bh & 3;
  const int tid = threadIdx.x, wv = tid >> 6, lane = tid & 63;
  const int lrow = lane & 15, quad = lane >> 4;
  const size_t base = (size_t)bh * TP * DHP;
  const float scale = 0.14433756729740643f;   // 1/sqrt(48)

  // Q fragments (A-layout): t = wv*64 + rg*16 + lrow, k(d) = ka*32 + quad*8
  bf16x8 qf[4][2];
  #pragma unroll
  for (int rg=0; rg<4; rg++)
    #pragma unroll
    for (int ka=0; ka<2; ka++)
      qf[rg][ka] = as_bf(*(const u16x8*)(Qg + base + (size_t)(wv*64+rg*16+lrow)*DHP + ka*32 + quad*8));

  // stage K rows 0..207: segs 0..5 = data, segs 6..7 = zeros (d pad)
  for (int it=0; it<5; it++) {
    int slot = it*256 + tid;
    if (slot < 1248) {
      int t = slot/6, sg = slot - t*6;
      u16x8 v = *(const u16x8*)(Kg + base + (size_t)t*DHP + sg*8);
      *(u16x8*)&Ks[t*KSTR + sg*8] = v;
    }
  }
  {
    u16x8 z = {0,0,0,0,0,0,0,0};
    for (int it=0; it<2; it++) {
      int slot = it*256 + tid;
      if (slot < 416) { int t = slot>>1, sg = 6 + (slot&1);
        *(u16x8*)&Ks[t*KSTR + sg*8] = z; }
    }
  }
  // stage V transposed: Vs[d][t], d<48, t<208
  for (int it=0; it<5; it++) {
    int slot = it*256 + tid;
    if (slot < 1248) {
      int sg = slot/208, t = slot - sg*208;
      u16x8 v = *(const u16x8*)(Vg + base + (size_t)t*DHP + sg*8);
      #pragma unroll
      for (int j=0;j<8;j++) Vs[(sg*8+j)*VSTR + t] = v[j];
    }
  }
  __syncthreads();

  f32x4 o[4][3];
  float m_i[4][4], l_i[4][4];
  #pragma unroll
  for (int rg=0;rg<4;rg++) {
    #pragma unroll
    for (int dg=0;dg<3;dg++) { f32x4 z = {0.f,0.f,0.f,0.f}; o[rg][dg] = z; }
    #pragma unroll
    for (int r=0;r<4;r++) { m_i[rg][r] = -1e30f; l_i[rg][r] = 0.f; }
  }
  u16* PwA = &Ps[(wv*2 + 0)*16*PSTR];
  u16* PwB = &Ps[(wv*2 + 1)*16*PSTR];

  #pragma unroll
  for (int c=0; c<4; c++) {
    const int NC = (c<3) ? 4 : 1;     // chunk 3: only cols 192..207 can be valid
    f32x4 s[4][4];
    #pragma unroll
    for (int rg=0;rg<4;rg++)
      #pragma unroll
      for (int cg=0;cg<4;cg++) if (cg < NC) { f32x4 z = {0.f,0.f,0.f,0.f}; s[rg][cg] = z; }

    // S chunk = Q @ K^T
    #pragma unroll
    for (int cg=0;cg<4;cg++) if (cg < NC) {
      #pragma unroll
      for (int ka=0; ka<2; ka++) {
        bf16x8 kf = as_bf(*(const u16x8*)&Ks[(c*64+cg*16+lrow)*KSTR + ka*32 + quad*8]);
        #pragma unroll
        for (int rg=0;rg<4;rg++)
          s[rg][cg] = __builtin_amdgcn_mfma_f32_16x16x32_bf16(qf[rg][ka], kf, s[rg][cg], 0,0,0);
      }
    }

    // per row-group: (a) softmax compute (no o), (b) deferred PV of it-1,
    // (c) rescale o, (d) write P into bank it&1
    #pragma unroll
    for (int rg=0;rg<4;rg++) {
      const int it  = c*4 + rg;
      if (c == 3) {
        #pragma unroll
        for (int r=0;r<4;r++) s[rg][0][r] = (lrow >= 5) ? -1e30f : s[rg][0][r];
      }
      // (a) max/exp/l/m -- does not touch o
      float mnew[4], al[4];
      #pragma unroll
      for (int r=0;r<4;r++) {
        float mc = s[rg][0][r];
        #pragma unroll
        for (int cg=1;cg<4;cg++) if (cg < NC) mc = fmaxf(mc, s[rg][cg][r]);
        #pragma unroll
        for (int sh=1; sh<16; sh<<=1) mc = fmaxf(mc, __shfl_xor(mc, sh, 64));
        float mo = m_i[rg][r];
        float mn = fmaxf(mo, mc);
        mnew[r] = mn;
        al[r] = __expf((mo - mn)*scale);
      }
      #pragma unroll
      for (int r=0;r<4;r++) {
        float acc = 0.f;
        #pragma unroll
        for (int cg=0;cg<4;cg++) if (cg < NC) {
          float p = __expf((s[rg][cg][r] - mnew[r])*scale);
          s[rg][cg][r] = p;
          acc += p;
        }
        #pragma unroll
        for (int sh=1; sh<16; sh<<=1) acc += __shfl_xor(acc, sh, 64);
        l_i[rg][r] = l_i[rg][r]*al[r] + acc;
        m_i[rg][r] = mnew[r];
      }

      // (b) deferred PV of pending iteration it-1 (adds chunk-ppc contribution
      //     to o[pprg] BEFORE o[rg]'s rescale below -- required when pprg==rg)
      if (it > 0) {
        const int pit = it - 1, ppc = pit >> 2, pprg = pit & 3;
        const int NKp = (ppc < 3) ? 2 : 1;
        const u16* Pr = (pit & 1) ? PwB : PwA;
        __builtin_amdgcn_s_waitcnt(0xC07F);   // pending writes issued a full softmax ago
        #pragma unroll
        for (int ka=0; ka<2; ka++) if (ka < NKp) {
          bf16x8 pf = as_bf(*(const u16x8*)&Pr[lrow*PSTR + ka*32 + quad*8]);
          #pragma unroll
          for (int dg=0;dg<3;dg++) {
            bf16x8 vf = as_bf(*(const u16x8*)&Vs[(dg*16+lrow)*VSTR + ppc*64 + ka*32 + quad*8]);
            o[pprg][dg] = __builtin_amdgcn_mfma_f32_16x16x32_bf16(pf, vf, o[pprg][dg], 0,0,0);
          }
        }
      }

      // (c) rescale o[rg] to the new max
      #pragma unroll
      for (int dg=0;dg<3;dg++)
        #pragma unroll
        for (int r=0;r<4;r++) o[rg][dg][r] *= al[r];

      // (d) write P(c,rg) into bank it&1 (read next iteration)
      u16* Pd = (it & 1) ? PwB : PwA;
      #pragma unroll
      for (int cg=0;cg<4;cg++) if (cg < NC) {
        #pragma unroll
        for (int r=0;r<4;r++)
          Pd[(quad*4+r)*PSTR + cg*16 + lrow] = f2b(s[rg][cg][r]);
      }
      if (c == 3) {
        #pragma unroll
        for (int r=0;r<4;r++) Pd[(quad*4+r)*PSTR + 16 + lrow] = 0;
      }
    }
  }
  // final pending PV: it=15 -> ppc=3, pprg=3, NK=1, bank B
  {
    __builtin_amdgcn_s_waitcnt(0xC07F);
    bf16x8 pf = as_bf(*(const u16x8*)&PwB[lrow*PSTR + quad*8]);
    #pragma unroll
    for (int dg=0;dg<3;dg++) {
      bf16x8 vf = as_bf(*(const u16x8*)&Vs[(dg*16+lrow)*VSTR + 3*64 + quad*8]);
      o[3][dg] = __builtin_amdgcn_mfma_f32_16x16x32_bf16(pf, vf, o[3][dg], 0,0,0);
    }
  }

  // epilogue: O /= l, store rows t<197, cols d<48
  #pragma unroll
  for (int rg=0;rg<4;rg++) {
    #pragma unroll
    for (int r=0;r<4;r++) {
      int t = wv*64 + rg*16 + quad*4 + r;
      if (t < 197) {
        float inv = 1.0f / l_i[rg][r];
        u16* dst = Og + ((size_t)(b*197) + t)*DD + h*48;
        #pragma unroll
        for (int dg=0;dg<3;dg++) dst[dg*16 + lrow] = f2b(o[rg][dg][r]*inv);
      }
    }
  }
}

// ---------- small kernels ----------
// all weight fp32->bf16 conversions in one launch (incl. head pad-to-zero)
__global__ void cvt5_k(const float* __restrict__ a, const float* __restrict__ b,
                       const float* __restrict__ c, const float* __restrict__ d,
                       const float* __restrict__ e,
                       u16* __restrict__ oa, u16* __restrict__ ob, u16* __restrict__ oc,
                       u16* __restrict__ od, u16* __restrict__ oe) {
  int i = blockIdx.x*256 + threadIdx.x;
  if (i < 147456) { oa[i] = f2b(a[i]); return; } i -= 147456;
  if (i < 110592) { ob[i] = f2b(b[i]); return; } i -= 110592;
  if (i < 442368) { oc[i] = f2b(c[i]); return; } i -= 442368;
  if (i < 442368) { od[i] = f2b(d[i]); return; } i -= 442368;
  if (i < 196608) { oe[i] = (i < 192000) ? f2b(e[i]) : (u16)0; }
}

__global__ void im2col_k(const float* __restrict__ x, u16* __restrict__ P) {
  int id = blockIdx.x*256 + threadIdx.x;
  int w8 = id % 28; int r = id / 28;
  int h  = r % 224; r /= 224;
  int c  = r % 3;   int b = r / 3;
  const float* src = x + (((size_t)(b*3 + c)*224 + h)*224 + w8*8);
  float4 a  = *(const float4*)src;
  float4 bb = *(const float4*)(src + 4);
  int pr = h >> 4, i = h & 15, pc = (w8*8) >> 4, j0 = (w8*8) & 15;
  u16* dst = P + ((size_t)(b*196) + pr*14 + pc)*768 + (c*256 + i*16 + j0);
  u16x8 o;
  o[0]=f2b(a.x); o[1]=f2b(a.y); o[2]=f2b(a.z); o[3]=f2b(a.w);
  o[4]=f2b(bb.x); o[5]=f2b(bb.y); o[6]=f2b(bb.z); o[7]=f2b(bb.w);
  *(u16x8*)dst = o;
}

__global__ void cls_k(const float* __restrict__ cls_tok, const float* __restrict__ pos, u16* __restrict__ tok) {
  int b = blockIdx.x, d = threadIdx.x;
  tok[((size_t)b*197)*DD + d] = f2b(cls_tok[d] + pos[d]);
}

__global__ void fusew_k(const float* __restrict__ in_w, const float* __restrict__ q_w,
                        const float* __restrict__ k_w, const float* __restrict__ v_w,
                        u16* __restrict__ weff) {
  int i = blockIdx.x, p = blockIdx.y, n = blockIdx.z;
  int k = threadIdx.x;
  const float* wrow = in_w + ((size_t)i*576 + p*192 + n)*192;
  const float* Bm = (p==0 ? q_w : (p==1 ? k_w : v_w)) + (size_t)i*192*192;
  float acc = 0.f;
  for (int m=0;m<192;m++) acc += wrow[m] * Bm[m*192 + k];
  weff[((size_t)i*576 + p*192 + n)*192 + k] = f2b(acc);
}

__global__ void fuseb_k(const float* __restrict__ in_w, const float* __restrict__ q_b,
                        const float* __restrict__ k_b, const float* __restrict__ v_b,
                        const float* __restrict__ in_b, float* __restrict__ effb) {
  int i = blockIdx.x, n = threadIdx.x;
  int p = n / 192;
  const float* bb = (p==0 ? q_b : (p==1 ? k_b : v_b)) + i*192;
  const float* wrow = in_w + ((size_t)i*576 + n)*192;
  float acc = in_b[i*576 + n];
  for (int m=0;m<192;m++) acc += wrow[m]*bb[m];
  effb[i*576 + n] = acc;
}

// ---------- orchestration ----------
extern "C" void kernel_launch(void* const* d_in, const int* in_sizes, int n_in,
                              void* d_out, int out_size, void* d_ws, size_t ws_size,
                              hipStream_t stream) {
  const float* x      = (const float*)d_in[0];
  const float* lm_w   = (const float*)d_in[1];
  const float* lm_b   = (const float*)d_in[2];
  const float* cls_t  = (const float*)d_in[3];
  const float* pos    = (const float*)d_in[4];
  const float* q_w    = (const float*)d_in[5];
  const float* q_b    = (const float*)d_in[6];
  const float* k_w    = (const float*)d_in[7];
  const float* k_b    = (const float*)d_in[8];
  const float* v_w    = (const float*)d_in[9];
  const float* v_b    = (const float*)d_in[10];
  const float* in_w   = (const float*)d_in[11];
  const float* in_b   = (const float*)d_in[12];
  const float* out_w  = (const float*)d_in[13];
  const float* out_b  = (const float*)d_in[14];
  const float* up_w   = (const float*)d_in[15];
  const float* up_b   = (const float*)d_in[16];
  const float* dn_w   = (const float*)d_in[17];
  const float* dn_b   = (const float*)d_in[18];
  const float* head_w = (const float*)d_in[19];
  const float* head_b = (const float*)d_in[20];

  char* ws = (char*)d_ws;
  size_t off = 0;
  auto alloc = [&](size_t elems, size_t esz) {
    void* p = ws + off; off += ((elems*esz + 255)/256)*256; return p;
  };
  u16*  big  = (u16*)alloc(BIG_E, 2);        // patches / mlp hidden
  u16*  tok  = (u16*)alloc(TOK_E, 2);
  u16*  qq   = (u16*)alloc(QKV_E*3, 2);      // q,k,v contiguous (b,h,t,d) padded
  u16*  obuf = (u16*)alloc(TOK_E, 2);
  u16*  lmw  = (u16*)alloc(147456, 2);
  u16*  outw = (u16*)alloc(110592, 2);
  u16*  upw  = (u16*)alloc(442368, 2);
  u16*  dnw  = (u16*)alloc(442368, 2);
  u16*  hdw  = (u16*)alloc(196608, 2);
  u16*  weff = (u16*)alloc(331776, 2);
  float* effb = (float*)alloc(1728, 4);
  (void)ws_size; (void)in_sizes; (void)n_in; (void)out_size;

  u16* kbuf = qq + QKV_E;
  u16* vbuf = qq + 2*QKV_E;

  // weight prep (one launch) + QKV weight fusion
  cvt5_k<<<(1339392+255)/256,256,0,stream>>>(lm_w, out_w, up_w, dn_w, head_w,
                                             lmw, outw, upw, dnw, hdw);
  fusew_k<<<dim3(3,3,192),192,0,stream>>>(in_w, q_w, k_w, v_w, weff);
  fuseb_k<<<3,576,0,stream>>>(in_w, q_b, k_b, v_b, in_b, effb);

  // patch embed + pos + cls   (grids are (nN, nM=M/128) for the XCD swizzle)
  im2col_k<<<18816,256,0,stream>>>(x, big);
  gemm4w<M_PATCH,false,false,true><<<dim3(3,MPAT/128,1),256,0,stream>>>(
      big, lmw, lm_b, nullptr, tok, pos, 768, 768, DD, DD, 0,0,0);
  cls_k<<<BATCH,DD,0,stream>>>(cls_t, pos, tok);

  for (int i=0;i<3;i++) {
    gemm4w<M_QKV,false,false,true><<<dim3(9,MTOK/128,1),256,0,stream>>>(
        tok, weff + (size_t)i*576*192, effb + i*576, nullptr, qq, nullptr,
        192, 192, 0, 576, 0,0,0);
    flash_k<<<1024,256,0,stream>>>(qq, kbuf, vbuf, obuf);
    gemm4w<M_BF16,false,true,true><<<dim3(3,MTOK/128,1),256,0,stream>>>(
        obuf, outw + (size_t)i*36864, out_b + i*192, tok, tok, nullptr,
        192, 192, DD, DD, 0,0,0);
    gemm4w<M_BF16,true,false,true><<<dim3(12,MTOK/128,1),256,0,stream>>>(
        tok, upw + (size_t)i*147456, up_b + i*768, nullptr, big, nullptr,
        192, 192, 768, 768, 0,0,0);
    gemm4w<M_BF16,false,false,true><<<dim3(3,MTOK/128,1),256,0,stream>>>(
        big, dnw + (size_t)i*147456, dn_b + i*192, nullptr, tok, nullptr,
        768, 768, DD, DD, 0,0,0);
  }
  gemm4w<M_F32,false,false,true><<<dim3(16,2,1),256,0,stream>>>(
      tok, hdw, head_b, nullptr, d_out, nullptr,
      192, 197*192, 1000, 1000, 0,0,0);
}

// Round 7
// 881.395 us; speedup vs baseline: 1.4192x; 1.1048x over previous
//
#include <hip/hip_runtime.h>

typedef unsigned short u16;
typedef __bf16 bf16x8 __attribute__((ext_vector_type(8)));
typedef float  f32x4  __attribute__((ext_vector_type(4)));
typedef u16    u16x8  __attribute__((ext_vector_type(8)));

// ---------- problem constants ----------
#define BATCH 256
#define TT    197          // tokens
#define TP    256          // padded tokens
#define DD    192          // model dim
#define DHP   64           // padded head dim (real 48)
#define MTOK  (BATCH*TT)   // 50432 rows = 197*256
#define MPAT  (BATCH*196)  // 50176 rows

constexpr size_t BIG_E  = 1024ull*256*256;   // patches 38.5M / mlp-h 38.7M
constexpr size_t TOK_E  = (size_t)MTOK*DD;
constexpr size_t QKV_E  = 1024ull*TP*DHP;    // per q/k/v tensor (padded)

__device__ __forceinline__ float b2f(u16 h){ union{unsigned u; float f;} x; x.u=(unsigned)h<<16; return x.f; }
__device__ __forceinline__ u16 f2b(float f){ union{float f; unsigned u;} x{f}; unsigned r = x.u + 0x7fffu + ((x.u>>16)&1u); return (u16)(r>>16); }
__device__ __forceinline__ bf16x8 as_bf(u16x8 v){ return __builtin_bit_cast(bf16x8, v); }

__device__ __forceinline__ void gload_lds16(const void* g, void* l) {
  __builtin_amdgcn_global_load_lds((__attribute__((address_space(1))) void*)(size_t)g,
                                   (__attribute__((address_space(3))) void*)l, 16, 0, 0);
}

// ---------- 4-wave 128x64-tile MFMA GEMM:  C = A(MxK) @ W(NxK)^T ----------
// 3-buffer, 2-deep prefetch, ONE barrier per K-step (T3/T4 deepened),
// XCD-chunked tile swizzle (T1/m204), T2 read/write LDS XOR swizzle.
enum { M_F32=0, M_BF16=1, M_QKV=2, M_PATCH=4 };

template<int MODE, bool RELU, bool RES, bool BIAS>
__global__ __launch_bounds__(256)
void gemm4w(const u16* __restrict__ A, const u16* __restrict__ W,
            const float* __restrict__ bias, const u16* __restrict__ res,
            void* __restrict__ Cout, const float* __restrict__ aux,
            int K, int lda, int ldc, int Nreal,
            long bA, long bW, long bC)
{
  __shared__ __align__(16) u16 As[3][128*32];   // 24 KB
  __shared__ __align__(16) u16 Ws[3][64*32];    // 12 KB
  const int tid  = threadIdx.x;
  const int wv   = tid >> 6;
  const int lane = tid & 63;

  // --- XCD-chunked bijective tile remap (pure permutation; z unused==0) ---
  const int nN  = gridDim.x, nM = gridDim.y;
  const int nwg = nN * nM;
  const int fid = blockIdx.x + nN * blockIdx.y;
  const int xcd = fid & 7, loc = fid >> 3;
  const int q8  = nwg >> 3, r8 = nwg & 7;
  const int tile = (xcd < r8 ? xcd * (q8 + 1) : r8 * (q8 + 1) + (xcd - r8) * q8) + loc;
  const int m0 = (tile / nN) * 128;
  const int n0 = (tile % nN) * 64;

  const int bz = blockIdx.z;
  const u16* Ab = A + (size_t)bz * (size_t)bA;
  const u16* Wb = W + (size_t)bz * (size_t)bW;

  const int lrow = lane & 15, quad = lane >> 4;
  const int srow = lane >> 2, sseg = lane & 3;
  const int wsw  = (srow >> 1) & 3;            // write-side swizzle (global pre-swizzle)
  const int rsw  = (lrow >> 1) & 3;            // read-side swizzle (same XOR)

  f32x4 acc[2][4];
  #pragma unroll
  for (int i=0;i<2;i++)
    #pragma unroll
    for (int j=0;j<4;j++) { f32x4 z = {0.f,0.f,0.f,0.f}; acc[i][j] = z; }

  auto stage = [&](int bufi, int k0) {
    #pragma unroll
    for (int i=0;i<2;i++) {
      const u16* ga = Ab + (size_t)(m0 + i*64 + wv*16 + srow)*lda + (k0 + (sseg^wsw)*8);
      gload_lds16(ga, &As[bufi][(i*64 + wv*16)*32]);
    }
    const u16* gw = Wb + (size_t)(n0 + wv*16 + srow)*K + (k0 + (sseg^wsw)*8);
    gload_lds16(gw, &Ws[bufi][(wv*16)*32]);
  };

  const int nt = K >> 5;                // K >= 192 -> nt >= 6
  stage(0, 0);
  stage(1, 32);                         // 2 tiles in flight (6 loads)
  for (int t = 0; t < nt; ++t) {
    if (t + 1 < nt) {
      asm volatile("s_waitcnt vmcnt(3)" ::: "memory");   // tile t done; t+1 in flight
    } else {
      asm volatile("s_waitcnt vmcnt(0)" ::: "memory");   // last tile: drain
    }
    asm volatile("s_barrier" ::: "memory");              // tile-t writes visible to all
    if (t + 2 < nt) stage((t + 2) % 3, (t + 2) << 5);    // overlaps with compute below

    const int cur = t % 3;
    bf16x8 af[2], wf[4];
    #pragma unroll
    for (int i=0;i<2;i++)
      af[i] = *(const bf16x8*)&As[cur][(wv*32 + i*16 + lrow)*32 + (quad^rsw)*8];
    #pragma unroll
    for (int i=0;i<4;i++)
      wf[i] = *(const bf16x8*)&Ws[cur][(i*16 + lrow)*32 + (quad^rsw)*8];
    #pragma unroll
    for (int mi=0;mi<2;mi++)
      #pragma unroll
      for (int ni=0;ni<4;ni++)
        acc[mi][ni] = __builtin_amdgcn_mfma_f32_16x16x32_bf16(af[mi], wf[ni], acc[mi][ni], 0,0,0);
  }

  #pragma unroll
  for (int mi=0;mi<2;mi++) {
    #pragma unroll
    for (int ni=0;ni<4;ni++) {
      #pragma unroll
      for (int r=0;r<4;r++) {
        int row = m0 + wv*32 + mi*16 + quad*4 + r;
        int col = n0 + ni*16 + lrow;
        float v = acc[mi][ni][r];
        if constexpr (MODE == M_F32) {
          if (col < Nreal) {
            if constexpr (BIAS) v += bias[col];
            ((float*)Cout)[(size_t)row*ldc + col] = v;
          }
        } else if constexpr (MODE == M_BF16) {
          if constexpr (BIAS) v += bias[col];
          if constexpr (RES)  v += b2f(res[(size_t)row*ldc + col]);
          if constexpr (RELU) v = v > 0.f ? v : 0.f;
          ((u16*)Cout)[(size_t)bz*(size_t)bC + (size_t)row*ldc + col] = f2b(v);
        } else if constexpr (MODE == M_QKV) {
          v += bias[col];
          int sel = col / 192, rem = col % 192;
          int h = rem / 48, d = rem % 48;
          int b = row / 197, t = row % 197;
          ((u16*)Cout)[(size_t)sel*QKV_E + ((size_t)(b*4 + h)*TP + t)*DHP + d] = f2b(v);
        } else if constexpr (MODE == M_PATCH) {
          int b = row / 196, p = row % 196;
          v += bias[col] + aux[(size_t)(1 + p)*DD + col];
          ((u16*)Cout)[((size_t)(b*197) + 1 + p)*DD + col] = f2b(v);
        }
      }
    }
  }
}

// ---------- fused flash attention: one workgroup per (b,h) ----------
// 8 waves x 32 Q-rows each (2 row-groups/wave). LDS: K 208x72 (29.9 KB),
// Vt 49x216 (21.2 KB), P 8 waves x 16x72 (18.4 KB) = 69.5 KB -> 2 blocks/CU,
// 16 waves/CU IF VGPR <= 128 (halved per-wave state; NO forced cap -- the
// round-1 failure is attributed to launch_bounds(512,4) spill codegen).
#define KSTR 72
#define VSTR 216
#define PSTR 72
#define TKR  208

__global__ __launch_bounds__(512)
void flash_k(const u16* __restrict__ Qg, const u16* __restrict__ Kg,
             const u16* __restrict__ Vg, u16* __restrict__ Og)
{
  __shared__ __align__(16) u16 Ks[TKR*KSTR];
  __shared__ __align__(16) u16 Vs[49*VSTR];
  __shared__ __align__(16) u16 Ps[8*16*PSTR];
  const int bh = blockIdx.x;
  const int b = bh >> 2, h = bh & 3;
  const int tid = threadIdx.x, wv = tid >> 6, lane = tid & 63;
  const int lrow = lane & 15, quad = lane >> 4;
  const size_t base = (size_t)bh * TP * DHP;
  const float scale = 0.14433756729740643f;   // 1/sqrt(48)

  // Q fragments (A-layout): t = wv*32 + rg*16 + lrow, k(d) = ka*32 + quad*8
  bf16x8 qf[2][2];
  #pragma unroll
  for (int rg=0; rg<2; rg++)
    #pragma unroll
    for (int ka=0; ka<2; ka++)
      qf[rg][ka] = as_bf(*(const u16x8*)(Qg + base + (size_t)(wv*32+rg*16+lrow)*DHP + ka*32 + quad*8));

  // stage K rows 0..207: segs 0..5 = data, segs 6..7 = zeros (d pad)
  #pragma unroll
  for (int it=0; it<3; it++) {
    int slot = it*512 + tid;
    if (slot < 1248) {
      int t = slot/6, sg = slot - t*6;
      u16x8 v = *(const u16x8*)(Kg + base + (size_t)t*DHP + sg*8);
      *(u16x8*)&Ks[t*KSTR + sg*8] = v;
    }
  }
  {
    u16x8 z = {0,0,0,0,0,0,0,0};
    if (tid < 416) { int t = tid>>1, sg = 6 + (tid&1);
      *(u16x8*)&Ks[t*KSTR + sg*8] = z; }
  }
  // stage V transposed: Vs[d][t], d<48, t<208
  #pragma unroll
  for (int it=0; it<3; it++) {
    int slot = it*512 + tid;
    if (slot < 1248) {
      int sg = slot/208, t = slot - sg*208;
      u16x8 v = *(const u16x8*)(Vg + base + (size_t)t*DHP + sg*8);
      #pragma unroll
      for (int j=0;j<8;j++) Vs[(sg*8+j)*VSTR + t] = v[j];
    }
  }
  __syncthreads();
  if (wv == 7) return;   // rows 224..255: none valid (T=197); staging done

  f32x4 o[2][3];
  float m_i[2][4], l_i[2][4];
  #pragma unroll
  for (int rg=0;rg<2;rg++) {
    #pragma unroll
    for (int dg=0;dg<3;dg++) { f32x4 z = {0.f,0.f,0.f,0.f}; o[rg][dg] = z; }
    #pragma unroll
    for (int r=0;r<4;r++) { m_i[rg][r] = -1e30f; l_i[rg][r] = 0.f; }
  }
  u16* Pw = &Ps[wv*16*PSTR];

  #pragma unroll
  for (int c=0; c<4; c++) {
    const int NC = (c<3) ? 4 : 1;     // chunk 3: only cols 192..207 can be valid
    f32x4 s[2][4];
    #pragma unroll
    for (int rg=0;rg<2;rg++)
      #pragma unroll
      for (int cg=0;cg<4;cg++) if (cg < NC) { f32x4 z = {0.f,0.f,0.f,0.f}; s[rg][cg] = z; }

    // S chunk = Q @ K^T
    #pragma unroll
    for (int cg=0;cg<4;cg++) if (cg < NC) {
      #pragma unroll
      for (int ka=0; ka<2; ka++) {
        bf16x8 kf = as_bf(*(const u16x8*)&Ks[(c*64+cg*16+lrow)*KSTR + ka*32 + quad*8]);
        #pragma unroll
        for (int rg=0;rg<2;rg++)
          s[rg][cg] = __builtin_amdgcn_mfma_f32_16x16x32_bf16(qf[rg][ka], kf, s[rg][cg], 0,0,0);
      }
    }

    // online softmax + PV, per row-group
    #pragma unroll
    for (int rg=0;rg<2;rg++) {
      if (c == 3) {
        #pragma unroll
        for (int r=0;r<4;r++) s[rg][0][r] = (lrow >= 5) ? -1e30f : s[rg][0][r];
      }
      float mnew[4], al[4];
      #pragma unroll
      for (int r=0;r<4;r++) {
        float mc = s[rg][0][r];
        #pragma unroll
        for (int cg=1;cg<4;cg++) if (cg < NC) mc = fmaxf(mc, s[rg][cg][r]);
        #pragma unroll
        for (int sh=1; sh<16; sh<<=1) mc = fmaxf(mc, __shfl_xor(mc, sh, 64));
        float mo = m_i[rg][r];
        float mn = fmaxf(mo, mc);
        mnew[r] = mn;
        al[r] = __expf((mo - mn)*scale);
      }
      #pragma unroll
      for (int r=0;r<4;r++) {
        float acc = 0.f;
        #pragma unroll
        for (int cg=0;cg<4;cg++) if (cg < NC) {
          float p = __expf((s[rg][cg][r] - mnew[r])*scale);
          s[rg][cg][r] = p;
          acc += p;
        }
        #pragma unroll
        for (int sh=1; sh<16; sh<<=1) acc += __shfl_xor(acc, sh, 64);
        l_i[rg][r] = l_i[rg][r]*al[r] + acc;
        m_i[rg][r] = mnew[r];
      }
      #pragma unroll
      for (int dg=0;dg<3;dg++)
        #pragma unroll
        for (int r=0;r<4;r++) o[rg][dg][r] *= al[r];

      // P (C-layout) -> LDS (row-major) for A-layout reads
      #pragma unroll
      for (int cg=0;cg<4;cg++) if (cg < NC) {
        #pragma unroll
        for (int r=0;r<4;r++)
          Pw[(quad*4+r)*PSTR + cg*16 + lrow] = f2b(s[rg][cg][r]);
      }
      if (c == 3) {
        #pragma unroll
        for (int r=0;r<4;r++) Pw[(quad*4+r)*PSTR + 16 + lrow] = 0;
      }
      __builtin_amdgcn_s_waitcnt(0xC07F);   // lgkmcnt(0)

      const int NK = (c<3) ? 2 : 1;
      #pragma unroll
      for (int ka=0; ka<2; ka++) if (ka < NK) {
        bf16x8 pf = as_bf(*(const u16x8*)&Pw[lrow*PSTR + ka*32 + quad*8]);
        #pragma unroll
        for (int dg=0;dg<3;dg++) {
          bf16x8 vf = as_bf(*(const u16x8*)&Vs[(dg*16+lrow)*VSTR + c*64 + ka*32 + quad*8]);
          o[rg][dg] = __builtin_amdgcn_mfma_f32_16x16x32_bf16(pf, vf, o[rg][dg], 0,0,0);
        }
      }
      __builtin_amdgcn_s_waitcnt(0xC07F);   // drain reads before next rg overwrites Pw
    }
  }

  // epilogue: O /= l, store rows t<197, cols d<48
  #pragma unroll
  for (int rg=0;rg<2;rg++) {
    #pragma unroll
    for (int r=0;r<4;r++) {
      int t = wv*32 + rg*16 + quad*4 + r;
      if (t < 197) {
        float inv = 1.0f / l_i[rg][r];
        u16* dst = Og + ((size_t)(b*197) + t)*DD + h*48;
        #pragma unroll
        for (int dg=0;dg<3;dg++) dst[dg*16 + lrow] = f2b(o[rg][dg][r]*inv);
      }
    }
  }
}

// ---------- small kernels ----------
// all weight fp32->bf16 conversions in one launch (incl. head pad-to-zero)
__global__ void cvt5_k(const float* __restrict__ a, const float* __restrict__ b,
                       const float* __restrict__ c, const float* __restrict__ d,
                       const float* __restrict__ e,
                       u16* __restrict__ oa, u16* __restrict__ ob, u16* __restrict__ oc,
                       u16* __restrict__ od, u16* __restrict__ oe) {
  int i = blockIdx.x*256 + threadIdx.x;
  if (i < 147456) { oa[i] = f2b(a[i]); return; } i -= 147456;
  if (i < 110592) { ob[i] = f2b(b[i]); return; } i -= 110592;
  if (i < 442368) { oc[i] = f2b(c[i]); return; } i -= 442368;
  if (i < 442368) { od[i] = f2b(d[i]); return; } i -= 442368;
  if (i < 196608) { oe[i] = (i < 192000) ? f2b(e[i]) : (u16)0; }
}

__global__ void im2col_k(const float* __restrict__ x, u16* __restrict__ P) {
  int id = blockIdx.x*256 + threadIdx.x;
  int w8 = id % 28; int r = id / 28;
  int h  = r % 224; r /= 224;
  int c  = r % 3;   int b = r / 3;
  const float* src = x + (((size_t)(b*3 + c)*224 + h)*224 + w8*8);
  float4 a  = *(const float4*)src;
  float4 bb = *(const float4*)(src + 4);
  int pr = h >> 4, i = h & 15, pc = (w8*8) >> 4, j0 = (w8*8) & 15;
  u16* dst = P + ((size_t)(b*196) + pr*14 + pc)*768 + (c*256 + i*16 + j0);
  u16x8 o;
  o[0]=f2b(a.x); o[1]=f2b(a.y); o[2]=f2b(a.z); o[3]=f2b(a.w);
  o[4]=f2b(bb.x); o[5]=f2b(bb.y); o[6]=f2b(bb.z); o[7]=f2b(bb.w);
  *(u16x8*)dst = o;
}

__global__ void cls_k(const float* __restrict__ cls_tok, const float* __restrict__ pos, u16* __restrict__ tok) {
  int b = blockIdx.x, d = threadIdx.x;
  tok[((size_t)b*197)*DD + d] = f2b(cls_tok[d] + pos[d]);
}

__global__ void fusew_k(const float* __restrict__ in_w, const float* __restrict__ q_w,
                        const float* __restrict__ k_w, const float* __restrict__ v_w,
                        u16* __restrict__ weff) {
  int i = blockIdx.x, p = blockIdx.y, n = blockIdx.z;
  int k = threadIdx.x;
  const float* wrow = in_w + ((size_t)i*576 + p*192 + n)*192;
  const float* Bm = (p==0 ? q_w : (p==1 ? k_w : v_w)) + (size_t)i*192*192;
  float acc = 0.f;
  for (int m=0;m<192;m++) acc += wrow[m] * Bm[m*192 + k];
  weff[((size_t)i*576 + p*192 + n)*192 + k] = f2b(acc);
}

__global__ void fuseb_k(const float* __restrict__ in_w, const float* __restrict__ q_b,
                        const float* __restrict__ k_b, const float* __restrict__ v_b,
                        const float* __restrict__ in_b, float* __restrict__ effb) {
  int i = blockIdx.x, n = threadIdx.x;
  int p = n / 192;
  const float* bb = (p==0 ? q_b : (p==1 ? k_b : v_b)) + i*192;
  const float* wrow = in_w + ((size_t)i*576 + n)*192;
  float acc = in_b[i*576 + n];
  for (int m=0;m<192;m++) acc += wrow[m]*bb[m];
  effb[i*576 + n] = acc;
}

// ---------- orchestration ----------
extern "C" void kernel_launch(void* const* d_in, const int* in_sizes, int n_in,
                              void* d_out, int out_size, void* d_ws, size_t ws_size,
                              hipStream_t stream) {
  const float* x      = (const float*)d_in[0];
  const float* lm_w   = (const float*)d_in[1];
  const float* lm_b   = (const float*)d_in[2];
  const float* cls_t  = (const float*)d_in[3];
  const float* pos    = (const float*)d_in[4];
  const float* q_w    = (const float*)d_in[5];
  const float* q_b    = (const float*)d_in[6];
  const float* k_w    = (const float*)d_in[7];
  const float* k_b    = (const float*)d_in[8];
  const float* v_w    = (const float*)d_in[9];
  const float* v_b    = (const float*)d_in[10];
  const float* in_w   = (const float*)d_in[11];
  const float* in_b   = (const float*)d_in[12];
  const float* out_w  = (const float*)d_in[13];
  const float* out_b  = (const float*)d_in[14];
  const float* up_w   = (const float*)d_in[15];
  const float* up_b   = (const float*)d_in[16];
  const float* dn_w   = (const float*)d_in[17];
  const float* dn_b   = (const float*)d_in[18];
  const float* head_w = (const float*)d_in[19];
  const float* head_b = (const float*)d_in[20];

  char* ws = (char*)d_ws;
  size_t off = 0;
  auto alloc = [&](size_t elems, size_t esz) {
    void* p = ws + off; off += ((elems*esz + 255)/256)*256; return p;
  };
  u16*  big  = (u16*)alloc(BIG_E, 2);        // patches / mlp hidden
  u16*  tok  = (u16*)alloc(TOK_E, 2);
  u16*  qq   = (u16*)alloc(QKV_E*3, 2);      // q,k,v contiguous (b,h,t,d) padded
  u16*  obuf = (u16*)alloc(TOK_E, 2);
  u16*  lmw  = (u16*)alloc(147456, 2);
  u16*  outw = (u16*)alloc(110592, 2);
  u16*  upw  = (u16*)alloc(442368, 2);
  u16*  dnw  = (u16*)alloc(442368, 2);
  u16*  hdw  = (u16*)alloc(196608, 2);
  u16*  weff = (u16*)alloc(331776, 2);
  float* effb = (float*)alloc(1728, 4);
  (void)ws_size; (void)in_sizes; (void)n_in; (void)out_size;

  u16* kbuf = qq + QKV_E;
  u16* vbuf = qq + 2*QKV_E;

  // weight prep (one launch) + QKV weight fusion
  cvt5_k<<<(1339392+255)/256,256,0,stream>>>(lm_w, out_w, up_w, dn_w, head_w,
                                             lmw, outw, upw, dnw, hdw);
  fusew_k<<<dim3(3,3,192),192,0,stream>>>(in_w, q_w, k_w, v_w, weff);
  fuseb_k<<<3,576,0,stream>>>(in_w, q_b, k_b, v_b, in_b, effb);

  // patch embed + pos + cls   (grids are (nN, nM=M/128) for the XCD swizzle)
  im2col_k<<<18816,256,0,stream>>>(x, big);
  gemm4w<M_PATCH,false,false,true><<<dim3(3,MPAT/128,1),256,0,stream>>>(
      big, lmw, lm_b, nullptr, tok, pos, 768, 768, DD, DD, 0,0,0);
  cls_k<<<BATCH,DD,0,stream>>>(cls_t, pos, tok);

  for (int i=0;i<3;i++) {
    gemm4w<M_QKV,false,false,true><<<dim3(9,MTOK/128,1),256,0,stream>>>(
        tok, weff + (size_t)i*576*192, effb + i*576, nullptr, qq, nullptr,
        192, 192, 0, 576, 0,0,0);
    flash_k<<<1024,512,0,stream>>>(qq, kbuf, vbuf, obuf);
    gemm4w<M_BF16,false,true,true><<<dim3(3,MTOK/128,1),256,0,stream>>>(
        obuf, outw + (size_t)i*36864, out_b + i*192, tok, tok, nullptr,
        192, 192, DD, DD, 0,0,0);
    gemm4w<M_BF16,true,false,true><<<dim3(12,MTOK/128,1),256,0,stream>>>(
        tok, upw + (size_t)i*147456, up_b + i*768, nullptr, big, nullptr,
        192, 192, 768, 768, 0,0,0);
    gemm4w<M_BF16,false,false,true><<<dim3(3,MTOK/128,1),256,0,stream>>>(
        big, dnw + (size_t)i*147456, dn_b + i*192, nullptr, tok, nullptr,
        768, 768, DD, DD, 0,0,0);
  }
  gemm4w<M_F32,false,false,true><<<dim3(16,2,1),256,0,stream>>>(
      tok, hdw, head_b, nullptr, d_out, nullptr,
      192, 197*192, 1000, 1000, 0,0,0);
}